// Round 1
// baseline (5015.028 us; speedup 1.0000x reference)
//
#include <hip/hip_runtime.h>
#include <hip/hip_bf16.h>
#include <math.h>

// Problem constants
#define BB 4
#define LL 1024
#define DD 1024
#define HH 16
#define DHH 64
#define FFF 4096
#define MM (BB*LL)   // 4096 rows

// ---------------- block reduction helpers ----------------
__device__ __forceinline__ float block_reduce_sum(float v, float* red, int tid) {
    red[tid] = v;
    __syncthreads();
    for (int off = 128; off > 0; off >>= 1) {
        if (tid < off) red[tid] += red[tid + off];
        __syncthreads();
    }
    float r = red[0];
    __syncthreads();
    return r;
}

__device__ __forceinline__ float block_reduce_max(float v, float* red, int tid) {
    red[tid] = v;
    __syncthreads();
    for (int off = 128; off > 0; off >>= 1) {
        if (tid < off) red[tid] = fmaxf(red[tid], red[tid + off]);
        __syncthreads();
    }
    float r = red[0];
    __syncthreads();
    return r;
}

// ---------------- fp32 tiled GEMM with bias (+optional relu) ----------------
// C[M,N] = A[M,K] @ W[K,N] + bias[N]   (all row-major)
// Block tile 64x64, BK=16, 256 threads, 4x4 micro-tile per thread.
__global__ __launch_bounds__(256)
void gemm_bias(const float* __restrict__ A, const float* __restrict__ W,
               const float* __restrict__ bias, float* __restrict__ C,
               int M, int N, int K, int relu) {
    __shared__ __align__(16) float As[16][68];  // [k][m], pad to 68 (272B rows: 16B aligned)
    __shared__ __align__(16) float Bs[16][68];  // [k][n]

    const int bm = blockIdx.y * 64;
    const int bn = blockIdx.x * 64;
    const int tid = threadIdx.x;
    const int tm = (tid >> 4) * 4;   // 0..60
    const int tn = (tid & 15) * 4;   // 0..60

    float acc[4][4] = {};

    // A-tile load indices: one float4 per thread (64x16 tile = 1024 floats)
    const int am = tid >> 2;            // row in tile 0..63
    const int ak = (tid & 3) * 4;       // k offset 0..12
    // B-tile load indices: one float4 per thread (16x64 tile)
    const int bk = tid >> 4;            // k 0..15
    const int bn4 = (tid & 15) * 4;     // n offset 0..60

    for (int k0 = 0; k0 < K; k0 += 16) {
        float4 av = *(const float4*)&A[(size_t)(bm + am) * K + k0 + ak];
        As[ak + 0][am] = av.x;
        As[ak + 1][am] = av.y;
        As[ak + 2][am] = av.z;
        As[ak + 3][am] = av.w;
        float4 wv = *(const float4*)&W[(size_t)(k0 + bk) * N + bn + bn4];
        *(float4*)&Bs[bk][bn4] = wv;
        __syncthreads();

        #pragma unroll
        for (int k = 0; k < 16; ++k) {
            float4 a4 = *(float4*)&As[k][tm];
            float4 b4 = *(float4*)&Bs[k][tn];
            float a[4] = {a4.x, a4.y, a4.z, a4.w};
            float b[4] = {b4.x, b4.y, b4.z, b4.w};
            #pragma unroll
            for (int i = 0; i < 4; ++i)
                #pragma unroll
                for (int j = 0; j < 4; ++j)
                    acc[i][j] = fmaf(a[i], b[j], acc[i][j]);
        }
        __syncthreads();
    }

    #pragma unroll
    for (int i = 0; i < 4; ++i) {
        const int m = bm + tm + i;
        #pragma unroll
        for (int j = 0; j < 4; ++j) {
            const int n = bn + tn + j;
            float v = acc[i][j] + bias[n];
            if (relu) v = fmaxf(v, 0.0f);
            C[(size_t)m * N + n] = v;
        }
    }
}

// ---------------- attention: one block per (b,h,q) row ----------------
// score = (q.k)/8 * bias[b,q,k]; mask==0 -> -10000; softmax; ctx = p @ V_h
__global__ __launch_bounds__(256)
void attn_kernel(const float* __restrict__ Q, const float* __restrict__ Km,
                 const float* __restrict__ Vm, const float* __restrict__ bias,
                 const int* __restrict__ mask, float* __restrict__ ctx) {
    const int idx = blockIdx.x;
    const int q = idx & (LL - 1);
    const int h = (idx >> 10) & (HH - 1);
    const int b = idx >> 14;
    const int tid = threadIdx.x;

    __shared__ __align__(16) float s[LL];
    __shared__ __align__(16) float qv[DHH];
    __shared__ float red[256];
    __shared__ float psum[4][DHH];

    const float* qptr = Q + ((size_t)(b * LL + q)) * DD + h * DHH;
    if (tid < 16) ((float4*)qv)[tid] = ((const float4*)qptr)[tid];
    __syncthreads();

    const float* bias_row = bias + ((size_t)(b * LL + q)) * LL;
    const int* mrow = mask + b * LL;

    // phase 1: scores
    float lmax = -3.4e38f;
    for (int k = tid; k < LL; k += 256) {
        const float4* kp = (const float4*)(Km + ((size_t)(b * LL + k)) * DD + h * DHH);
        float dot = 0.0f;
        #pragma unroll
        for (int i = 0; i < 16; ++i) {
            float4 kv = kp[i];
            float4 qq = ((float4*)qv)[i];
            dot = fmaf(qq.x, kv.x, dot);
            dot = fmaf(qq.y, kv.y, dot);
            dot = fmaf(qq.z, kv.z, dot);
            dot = fmaf(qq.w, kv.w, dot);
        }
        float sc = dot * 0.125f * bias_row[k];
        if (mrow[k] == 0) sc = -10000.0f;
        s[k] = sc;
        lmax = fmaxf(lmax, sc);
    }
    const float mx = block_reduce_max(lmax, red, tid);

    // phase 2: softmax numerator + denominator
    float lsum = 0.0f;
    for (int k = tid; k < LL; k += 256) {
        float p = __expf(s[k] - mx);
        s[k] = p;
        lsum += p;
    }
    const float ssum = block_reduce_sum(lsum, red, tid);
    const float inv = 1.0f / ssum;

    // phase 3: ctx = p @ V   (4 key-chunks x 64 dims)
    const int c = tid >> 6;   // 0..3
    const int d = tid & 63;
    float acc = 0.0f;
    const float* vbase = Vm + ((size_t)(b * LL)) * DD + h * DHH + d;
    #pragma unroll 8
    for (int k = c * 256; k < (c + 1) * 256; ++k) {
        acc = fmaf(s[k], vbase[(size_t)k * DD], acc);
    }
    psum[c][d] = acc;
    __syncthreads();
    if (tid < 64) {
        float r = (psum[0][tid] + psum[1][tid] + psum[2][tid] + psum[3][tid]) * inv;
        ctx[((size_t)(b * LL + q)) * DD + h * DHH + tid] = r;
    }
}

// ---------------- residual add + LayerNorm ----------------
// out = gamma * (v - mean) / sqrt(var + eps) + beta,  v = a + b (per row of 1024)
__global__ __launch_bounds__(256)
void add_ln_kernel(const float* __restrict__ a, const float* __restrict__ bres,
                   const float* __restrict__ gamma, const float* __restrict__ beta,
                   float* __restrict__ out) {
    const int row = blockIdx.x;
    const int tid = threadIdx.x;
    __shared__ float red[256];

    const size_t base = (size_t)row * DD;
    float v[4];
    float sum = 0.0f;
    #pragma unroll
    for (int i = 0; i < 4; ++i) {
        const int col = tid + i * 256;
        v[i] = a[base + col] + bres[base + col];
        sum += v[i];
    }
    const float mean = block_reduce_sum(sum, red, tid) * (1.0f / 1024.0f);
    float vs = 0.0f;
    #pragma unroll
    for (int i = 0; i < 4; ++i) {
        const float dlt = v[i] - mean;
        vs += dlt * dlt;
    }
    const float var = block_reduce_sum(vs, red, tid) * (1.0f / 1024.0f);
    const float rstd = rsqrtf(var + 1e-12f);
    #pragma unroll
    for (int i = 0; i < 4; ++i) {
        const int col = tid + i * 256;
        out[base + col] = gamma[col] * (v[i] - mean) * rstd + beta[col];
    }
}

extern "C" void kernel_launch(void* const* d_in, const int* in_sizes, int n_in,
                              void* d_out, int out_size, void* d_ws, size_t ws_size,
                              hipStream_t stream) {
    const float* x         = (const float*)d_in[0];
    const float* attn_bias = (const float*)d_in[1];
    const int*   src_mask  = (const int*)  d_in[2];
    const float* wq = (const float*)d_in[3];
    const float* bq = (const float*)d_in[4];
    const float* wk = (const float*)d_in[5];
    const float* bk = (const float*)d_in[6];
    const float* wv = (const float*)d_in[7];
    const float* bv = (const float*)d_in[8];
    const float* wo = (const float*)d_in[9];
    const float* bo = (const float*)d_in[10];
    const float* gamma1 = (const float*)d_in[11];
    const float* beta1  = (const float*)d_in[12];
    const float* w1 = (const float*)d_in[13];
    const float* b1 = (const float*)d_in[14];
    const float* w2 = (const float*)d_in[15];
    const float* b2 = (const float*)d_in[16];
    const float* gamma2 = (const float*)d_in[17];
    const float* beta2  = (const float*)d_in[18];
    float* out = (float*)d_out;

    // workspace layout (fp32 elements). Peak = 24M floats = 96 MB.
    float* ws = (float*)d_ws;
    const size_t M4 = (size_t)MM * DD;   // 4M elements = 16 MB
    float* Qb = ws + 0 * M4;
    float* Kb = ws + 1 * M4;
    float* Vb = ws + 2 * M4;
    float* Cx = ws + 3 * M4;   // attention context
    float* Ao = ws + 4 * M4;   // attn_out
    float* Hb = ws + 5 * M4;   // h (live until final LN)
    float* F1 = ws + 0 * M4;   // 16M floats: reuses Q..Cx (dead after WO gemm)
    float* F2 = ws + 4 * M4;   // reuses Ao (dead after LN1)

    dim3 blk(256);

    // QKV projections: [4096,1024] @ [1024,1024]
    gemm_bias<<<dim3(16, 64), blk, 0, stream>>>(x, wq, bq, Qb, MM, DD, DD, 0);
    gemm_bias<<<dim3(16, 64), blk, 0, stream>>>(x, wk, bk, Kb, MM, DD, DD, 0);
    gemm_bias<<<dim3(16, 64), blk, 0, stream>>>(x, wv, bv, Vb, MM, DD, DD, 0);

    // attention: one block per (b,h,q)
    attn_kernel<<<dim3(BB * HH * LL), blk, 0, stream>>>(Qb, Kb, Vb, attn_bias, src_mask, Cx);

    // output projection
    gemm_bias<<<dim3(16, 64), blk, 0, stream>>>(Cx, wo, bo, Ao, MM, DD, DD, 0);

    // h = LN(x + attn_out)
    add_ln_kernel<<<dim3(MM), blk, 0, stream>>>(Ao, x, gamma1, beta1, Hb);

    // FFN
    gemm_bias<<<dim3(64, 64), blk, 0, stream>>>(Hb, w1, b1, F1, MM, FFF, DD, 1);
    gemm_bias<<<dim3(16, 64), blk, 0, stream>>>(F1, w2, b2, F2, MM, DD, FFF, 0);

    // out = LN(h + ffn)
    add_ln_kernel<<<dim3(MM), blk, 0, stream>>>(F2, Hb, gamma2, beta2, out);
}

// Round 2
// 1801.508 us; speedup vs baseline: 2.7838x; 2.7838x over previous
//
#include <hip/hip_runtime.h>
#include <hip/hip_bf16.h>
#include <math.h>

// Problem constants
#define BB 4
#define LL 1024
#define DD 1024
#define HH 16
#define DHH 64
#define FFF 4096
#define MM (BB*LL)   // 4096 rows

// ---------------- block reduction helper ----------------
__device__ __forceinline__ float block_reduce_sum(float v, float* red, int tid) {
    red[tid] = v;
    __syncthreads();
    for (int off = 128; off > 0; off >>= 1) {
        if (tid < off) red[tid] += red[tid + off];
        __syncthreads();
    }
    float r = red[0];
    __syncthreads();
    return r;
}

// ---------------- fp32 tiled GEMM with bias (+optional relu) ----------------
// C[M,N] = A[M,K] @ W[K,N] + bias[N]   (all row-major)
// Block tile 64x64, BK=16, 256 threads, 4x4 micro-tile per thread.
__global__ __launch_bounds__(256)
void gemm_bias(const float* __restrict__ A, const float* __restrict__ W,
               const float* __restrict__ bias, float* __restrict__ C,
               int M, int N, int K, int relu) {
    __shared__ __align__(16) float As[16][68];
    __shared__ __align__(16) float Bs[16][68];

    const int bm = blockIdx.y * 64;
    const int bn = blockIdx.x * 64;
    const int tid = threadIdx.x;
    const int tm = (tid >> 4) * 4;
    const int tn = (tid & 15) * 4;

    float acc[4][4] = {};

    const int am = tid >> 2;
    const int ak = (tid & 3) * 4;
    const int bk = tid >> 4;
    const int bn4 = (tid & 15) * 4;

    for (int k0 = 0; k0 < K; k0 += 16) {
        float4 av = *(const float4*)&A[(size_t)(bm + am) * K + k0 + ak];
        As[ak + 0][am] = av.x;
        As[ak + 1][am] = av.y;
        As[ak + 2][am] = av.z;
        As[ak + 3][am] = av.w;
        float4 wv = *(const float4*)&W[(size_t)(k0 + bk) * N + bn + bn4];
        *(float4*)&Bs[bk][bn4] = wv;
        __syncthreads();

        #pragma unroll
        for (int k = 0; k < 16; ++k) {
            float4 a4 = *(float4*)&As[k][tm];
            float4 b4 = *(float4*)&Bs[k][tn];
            float a[4] = {a4.x, a4.y, a4.z, a4.w};
            float b[4] = {b4.x, b4.y, b4.z, b4.w};
            #pragma unroll
            for (int i = 0; i < 4; ++i)
                #pragma unroll
                for (int j = 0; j < 4; ++j)
                    acc[i][j] = fmaf(a[i], b[j], acc[i][j]);
        }
        __syncthreads();
    }

    #pragma unroll
    for (int i = 0; i < 4; ++i) {
        const int m = bm + tm + i;
        #pragma unroll
        for (int j = 0; j < 4; ++j) {
            const int n = bn + tn + j;
            float v = acc[i][j] + bias[n];
            if (relu) v = fmaxf(v, 0.0f);
            C[(size_t)m * N + n] = v;
        }
    }
}

// ---------------- tiled flash-style attention ----------------
// Block = (b, h, 64-row q-tile). Iterate 16 k-tiles of 64 keys.
// Per tile: S = (Q.K^T)/8 * bias, mask; online softmax; O += P.V
__global__ __launch_bounds__(256)
void attn_tiled(const float* __restrict__ Q, const float* __restrict__ Km,
                const float* __restrict__ Vm, const float* __restrict__ bias,
                const int* __restrict__ mask, float* __restrict__ ctx) {
    const int q0 = blockIdx.x * 64;
    const int h  = blockIdx.y;
    const int b  = blockIdx.z;
    const int tid = threadIdx.x;
    const int tm = (tid >> 4) * 4;   // q sub-tile
    const int tn = (tid & 15) * 4;   // k (or d) sub-tile

    __shared__ __align__(16) float Qs[64][68];   // [d][q] transposed
    __shared__ __align__(16) float KVs[64][68];  // K: [d][k] transposed ; V: [k][d]
    __shared__ __align__(16) float Ps[64][68];   // [k][q]
    __shared__ float pm[4][64];
    __shared__ float rowm[64], rowl[64], rowa[64];

    const size_t head_off = (size_t)h * DHH;

    // ---- load Q tile (once), transposed into Qs[d][q] ----
    {
        const int row = tid >> 2;          // 0..63
        const int quarter = tid & 3;       // 0..3
        const float* qrow = Q + ((size_t)(b * LL + q0 + row)) * DD + head_off;
        #pragma unroll
        for (int i = 0; i < 4; ++i) {
            const int d0 = quarter * 16 + i * 4;
            float4 v = *(const float4*)&qrow[d0];
            Qs[d0 + 0][row] = v.x;
            Qs[d0 + 1][row] = v.y;
            Qs[d0 + 2][row] = v.z;
            Qs[d0 + 3][row] = v.w;
        }
    }
    if (tid < 64) {
        rowm[tid] = -3.4e38f;
        rowl[tid] = 0.0f;
    }

    float acc_o[4][4] = {};
    const float* bias_base = bias + ((size_t)b * LL) * LL;
    const int* mrow = mask + b * LL;

    for (int kt = 0; kt < 16; ++kt) {
        const int k0 = kt * 64;

        // ---- load K tile transposed into KVs[d][k] ----
        {
            const int row = tid >> 2;
            const int quarter = tid & 3;
            const float* krow = Km + ((size_t)(b * LL + k0 + row)) * DD + head_off;
            #pragma unroll
            for (int i = 0; i < 4; ++i) {
                const int d0 = quarter * 16 + i * 4;
                float4 v = *(const float4*)&krow[d0];
                KVs[d0 + 0][row] = v.x;
                KVs[d0 + 1][row] = v.y;
                KVs[d0 + 2][row] = v.z;
                KVs[d0 + 3][row] = v.w;
            }
        }
        __syncthreads();

        // ---- S = Q.K^T micro-tiled ----
        float acc_s[4][4] = {};
        #pragma unroll
        for (int d = 0; d < 64; ++d) {
            float4 a4 = *(float4*)&Qs[d][tm];
            float4 b4 = *(float4*)&KVs[d][tn];
            float a[4] = {a4.x, a4.y, a4.z, a4.w};
            float bb[4] = {b4.x, b4.y, b4.z, b4.w};
            #pragma unroll
            for (int i = 0; i < 4; ++i)
                #pragma unroll
                for (int j = 0; j < 4; ++j)
                    acc_s[i][j] = fmaf(a[i], bb[j], acc_s[i][j]);
        }
        // scale * bias, mask
        int4 mv = *(const int4*)&mrow[k0 + tn];
        const int mk[4] = {mv.x, mv.y, mv.z, mv.w};
        #pragma unroll
        for (int i = 0; i < 4; ++i) {
            const int q = q0 + tm + i;
            float4 bias4 = *(const float4*)&bias_base[(size_t)q * LL + k0 + tn];
            float bb[4] = {bias4.x, bias4.y, bias4.z, bias4.w};
            #pragma unroll
            for (int j = 0; j < 4; ++j) {
                float sc = acc_s[i][j] * 0.125f * bb[j];
                acc_s[i][j] = (mk[j] == 0) ? -10000.0f : sc;
            }
        }
        __syncthreads();   // KVs consumed; Ps free to write

        // ---- write raw S transposed to Ps[k][q]; load V tile into KVs[k][d] ----
        #pragma unroll
        for (int i = 0; i < 4; ++i)
            #pragma unroll
            for (int j = 0; j < 4; ++j)
                Ps[tn + j][tm + i] = acc_s[i][j];
        {
            const int row = tid >> 2;
            const int quarter = tid & 3;
            const float* vrow = Vm + ((size_t)(b * LL + k0 + row)) * DD + head_off;
            #pragma unroll
            for (int i = 0; i < 4; ++i) {
                const int d0 = quarter * 16 + i * 4;
                *(float4*)&KVs[row][d0] = *(const float4*)&vrow[d0];
            }
        }
        __syncthreads();

        // ---- online softmax: row max ----
        const int qi = tid & 63;
        const int grp = tid >> 6;
        {
            float m = -3.4e38f;
            #pragma unroll
            for (int k = 0; k < 16; ++k) m = fmaxf(m, Ps[grp * 16 + k][qi]);
            pm[grp][qi] = m;
        }
        __syncthreads();
        if (tid < 64) {
            float mt = fmaxf(fmaxf(pm[0][tid], pm[1][tid]), fmaxf(pm[2][tid], pm[3][tid]));
            float mo = rowm[tid];
            float mn = fmaxf(mo, mt);
            rowm[tid] = mn;
            rowa[tid] = __expf(mo - mn);   // 0 on first tile
        }
        __syncthreads();
        // ---- exp in place + row sum ----
        {
            float lsum = 0.0f;
            const float mn = rowm[qi];
            #pragma unroll
            for (int k = 0; k < 16; ++k) {
                float p = __expf(Ps[grp * 16 + k][qi] - mn);
                Ps[grp * 16 + k][qi] = p;
                lsum += p;
            }
            pm[grp][qi] = lsum;
        }
        __syncthreads();
        if (tid < 64)
            rowl[tid] = rowl[tid] * rowa[tid] + pm[0][tid] + pm[1][tid] + pm[2][tid] + pm[3][tid];

        // ---- rescale O accumulator by alpha ----
        float al[4];
        #pragma unroll
        for (int i = 0; i < 4; ++i) al[i] = rowa[tm + i];
        #pragma unroll
        for (int i = 0; i < 4; ++i)
            #pragma unroll
            for (int j = 0; j < 4; ++j)
                acc_o[i][j] *= al[i];

        // ---- O += P.V micro-tiled ----
        #pragma unroll
        for (int k = 0; k < 64; ++k) {
            float4 a4 = *(float4*)&Ps[k][tm];
            float4 b4 = *(float4*)&KVs[k][tn];
            float a[4] = {a4.x, a4.y, a4.z, a4.w};
            float bb[4] = {b4.x, b4.y, b4.z, b4.w};
            #pragma unroll
            for (int i = 0; i < 4; ++i)
                #pragma unroll
                for (int j = 0; j < 4; ++j)
                    acc_o[i][j] = fmaf(a[i], bb[j], acc_o[i][j]);
        }
        __syncthreads();   // KVs/Ps reused next tile; rowa/rowl stable
    }

    // ---- epilogue: divide by l, store ----
    #pragma unroll
    for (int i = 0; i < 4; ++i) {
        const float inv = 1.0f / rowl[tm + i];
        float4 o;
        o.x = acc_o[i][0] * inv;
        o.y = acc_o[i][1] * inv;
        o.z = acc_o[i][2] * inv;
        o.w = acc_o[i][3] * inv;
        *(float4*)&ctx[((size_t)(b * LL + q0 + tm + i)) * DD + head_off + tn] = o;
    }
}

// ---------------- residual add + LayerNorm ----------------
__global__ __launch_bounds__(256)
void add_ln_kernel(const float* __restrict__ a, const float* __restrict__ bres,
                   const float* __restrict__ gamma, const float* __restrict__ beta,
                   float* __restrict__ out) {
    const int row = blockIdx.x;
    const int tid = threadIdx.x;
    __shared__ float red[256];

    const size_t base = (size_t)row * DD;
    float v[4];
    float sum = 0.0f;
    #pragma unroll
    for (int i = 0; i < 4; ++i) {
        const int col = tid + i * 256;
        v[i] = a[base + col] + bres[base + col];
        sum += v[i];
    }
    const float mean = block_reduce_sum(sum, red, tid) * (1.0f / 1024.0f);
    float vs = 0.0f;
    #pragma unroll
    for (int i = 0; i < 4; ++i) {
        const float dlt = v[i] - mean;
        vs += dlt * dlt;
    }
    const float var = block_reduce_sum(vs, red, tid) * (1.0f / 1024.0f);
    const float rstd = rsqrtf(var + 1e-12f);
    #pragma unroll
    for (int i = 0; i < 4; ++i) {
        const int col = tid + i * 256;
        out[base + col] = gamma[col] * (v[i] - mean) * rstd + beta[col];
    }
}

extern "C" void kernel_launch(void* const* d_in, const int* in_sizes, int n_in,
                              void* d_out, int out_size, void* d_ws, size_t ws_size,
                              hipStream_t stream) {
    const float* x         = (const float*)d_in[0];
    const float* attn_bias = (const float*)d_in[1];
    const int*   src_mask  = (const int*)  d_in[2];
    const float* wq = (const float*)d_in[3];
    const float* bq = (const float*)d_in[4];
    const float* wk = (const float*)d_in[5];
    const float* bk = (const float*)d_in[6];
    const float* wv = (const float*)d_in[7];
    const float* bv = (const float*)d_in[8];
    const float* wo = (const float*)d_in[9];
    const float* bo = (const float*)d_in[10];
    const float* gamma1 = (const float*)d_in[11];
    const float* beta1  = (const float*)d_in[12];
    const float* w1 = (const float*)d_in[13];
    const float* b1 = (const float*)d_in[14];
    const float* w2 = (const float*)d_in[15];
    const float* b2 = (const float*)d_in[16];
    const float* gamma2 = (const float*)d_in[17];
    const float* beta2  = (const float*)d_in[18];
    float* out = (float*)d_out;

    float* ws = (float*)d_ws;
    const size_t M4 = (size_t)MM * DD;   // 4M elements = 16 MB
    float* Qb = ws + 0 * M4;
    float* Kb = ws + 1 * M4;
    float* Vb = ws + 2 * M4;
    float* Cx = ws + 3 * M4;
    float* Ao = ws + 4 * M4;
    float* Hb = ws + 5 * M4;
    float* F1 = ws + 0 * M4;   // reuses Q..Cx (dead after WO gemm)
    float* F2 = ws + 4 * M4;   // reuses Ao (dead after LN1)

    dim3 blk(256);

    gemm_bias<<<dim3(16, 64), blk, 0, stream>>>(x, wq, bq, Qb, MM, DD, DD, 0);
    gemm_bias<<<dim3(16, 64), blk, 0, stream>>>(x, wk, bk, Kb, MM, DD, DD, 0);
    gemm_bias<<<dim3(16, 64), blk, 0, stream>>>(x, wv, bv, Vb, MM, DD, DD, 0);

    attn_tiled<<<dim3(16, HH, BB), blk, 0, stream>>>(Qb, Kb, Vb, attn_bias, src_mask, Cx);

    gemm_bias<<<dim3(16, 64), blk, 0, stream>>>(Cx, wo, bo, Ao, MM, DD, DD, 0);
    add_ln_kernel<<<dim3(MM), blk, 0, stream>>>(Ao, x, gamma1, beta1, Hb);
    gemm_bias<<<dim3(64, 64), blk, 0, stream>>>(Hb, w1, b1, F1, MM, FFF, DD, 1);
    gemm_bias<<<dim3(16, 64), blk, 0, stream>>>(F1, w2, b2, F2, MM, DD, FFF, 0);
    add_ln_kernel<<<dim3(MM), blk, 0, stream>>>(F2, Hb, gamma2, beta2, out);
}

// Round 3
// 801.788 us; speedup vs baseline: 6.2548x; 2.2469x over previous
//
#include <hip/hip_runtime.h>
#include <hip/hip_bf16.h>
#include <math.h>

// Problem constants
#define BB 4
#define LL 1024
#define DD 1024
#define HH 16
#define DHH 64
#define FFF 4096
#define MM (BB*LL)     // 4096 rows
#define LDQ 3072       // fused QKV row stride

typedef __attribute__((ext_vector_type(8))) short short8;
typedef __attribute__((ext_vector_type(4))) float f32x4;

__device__ __forceinline__ ushort f2bf(float f) {
    __hip_bfloat16 h = __float2bfloat16(f);
    return *(ushort*)&h;
}

// ---------------- block reduction helper ----------------
__device__ __forceinline__ float block_reduce_sum(float v, float* red, int tid) {
    red[tid] = v;
    __syncthreads();
    for (int off = 128; off > 0; off >>= 1) {
        if (tid < off) red[tid] += red[tid + off];
        __syncthreads();
    }
    float r = red[0];
    __syncthreads();
    return r;
}

// ---------------- elementwise cast fp32 -> bf16 (float4 granularity) -------
__global__ __launch_bounds__(256)
void cast_bf16(const float* __restrict__ in, ushort* __restrict__ out) {
    const int i = blockIdx.x * 256 + threadIdx.x;
    float4 v = ((const float4*)in)[i];
    ushort4 o;
    o.x = f2bf(v.x); o.y = f2bf(v.y); o.z = f2bf(v.z); o.w = f2bf(v.w);
    ((ushort4*)out)[i] = o;
}

// ---------------- tiled transpose + cast: W[K][N] fp32 -> WT[N][K] bf16 ----
__global__ __launch_bounds__(256)
void transpose_cast(const float* __restrict__ W, ushort* __restrict__ WT,
                    int K, int N) {
    __shared__ float tile[32][33];
    const int n0 = blockIdx.x * 32, k0 = blockIdx.y * 32;
    const int t = threadIdx.x;
    const int r = t >> 3, c4 = (t & 7) * 4;
    float4 v = *(const float4*)&W[(size_t)(k0 + r) * N + n0 + c4];
    tile[r][c4 + 0] = v.x; tile[r][c4 + 1] = v.y;
    tile[r][c4 + 2] = v.z; tile[r][c4 + 3] = v.w;
    __syncthreads();
    ushort4 o;
    o.x = f2bf(tile[c4 + 0][r]);
    o.y = f2bf(tile[c4 + 1][r]);
    o.z = f2bf(tile[c4 + 2][r]);
    o.w = f2bf(tile[c4 + 3][r]);
    *(ushort4*)&WT[(size_t)(n0 + r) * K + k0 + c4] = o;
}

// ---------------- concat 3 bias vectors of 1024 ----------------
__global__ __launch_bounds__(256)
void concat3(const float* __restrict__ a, const float* __restrict__ b,
             const float* __restrict__ c, float* __restrict__ o) {
    const int i = blockIdx.x * 256 + threadIdx.x;   // 0..3071
    o[i] = (i < 1024) ? a[i] : ((i < 2048) ? b[i - 1024] : c[i - 2048]);
}

// ---------------- bf16 MFMA GEMM (m97 structure) ----------------
// C[M,N] = A[M,K](bf16,row-major) @ Bt[N,K](bf16)^T + bias, opt relu,
// out fp32 or bf16. 128x128 tile, BK=32, 256 threads = 4 waves (2x2 of 64x64).
__global__ __launch_bounds__(256)
void gemm_bf16(const ushort* __restrict__ A, const ushort* __restrict__ Bt,
               const float* __restrict__ bias, void* __restrict__ C,
               int M, int N, int K, int relu, int obf16) {
    __shared__ ushort Als[128 * 32];   // [row][k] 8 KB
    __shared__ ushort Bls[128 * 32];

    const int bm = blockIdx.y * 128;
    const int bn = blockIdx.x * 128;
    const int t = threadIdx.x;
    const int lane = t & 63;
    const int w = t >> 6;
    const int wm = (w >> 1) * 64;
    const int wn = (w & 1) * 64;
    const int fm = lane & 15;
    const int kg = lane >> 4;          // 0..3

    f32x4 acc[4][4] = {};

    for (int k0 = 0; k0 < K; k0 += 32) {
        // stage A,B tiles via async global->LDS, 16 B per lane
        #pragma unroll
        for (int j = 0; j < 2; ++j) {
            const int chunk = j * 256 + t;
            const int row = chunk >> 2, kc = chunk & 3;
            const ushort* ga = A + (size_t)(bm + row) * K + k0 + kc * 8;
            __builtin_amdgcn_global_load_lds(
                (const __attribute__((address_space(1))) void*)ga,
                (__attribute__((address_space(3))) void*)(Als + chunk * 8), 16, 0, 0);
            const ushort* gb = Bt + (size_t)(bn + row) * K + k0 + kc * 8;
            __builtin_amdgcn_global_load_lds(
                (const __attribute__((address_space(1))) void*)gb,
                (__attribute__((address_space(3))) void*)(Bls + chunk * 8), 16, 0, 0);
        }
        __syncthreads();   // drains vmcnt + barrier

        short8 af[4], bf[4];
        #pragma unroll
        for (int i = 0; i < 4; ++i)
            af[i] = *(const short8*)&Als[(wm + i * 16 + fm) * 32 + kg * 8];
        #pragma unroll
        for (int j = 0; j < 4; ++j)
            bf[j] = *(const short8*)&Bls[(wn + j * 16 + fm) * 32 + kg * 8];
        #pragma unroll
        for (int i = 0; i < 4; ++i)
            #pragma unroll
            for (int j = 0; j < 4; ++j)
                acc[i][j] = __builtin_amdgcn_mfma_f32_16x16x32_bf16(
                    af[i], bf[j], acc[i][j], 0, 0, 0);
        __syncthreads();   // LDS reused next iter
    }

    // epilogue: C/D layout col=lane&15, row=(lane>>4)*4+reg
    const int orow0 = (lane >> 4) * 4;
    const int ocol = lane & 15;
    #pragma unroll
    for (int j = 0; j < 4; ++j) {
        const int n = bn + wn + j * 16 + ocol;
        const float bv = bias[n];
        #pragma unroll
        for (int i = 0; i < 4; ++i) {
            #pragma unroll
            for (int r = 0; r < 4; ++r) {
                const int m = bm + wm + i * 16 + orow0 + r;
                float v = acc[i][j][r] + bv;
                if (relu) v = fmaxf(v, 0.0f);
                if (obf16)
                    ((ushort*)C)[(size_t)m * N + n] = f2bf(v);
                else
                    ((float*)C)[(size_t)m * N + n] = v;
            }
        }
    }
}

// ---------------- tiled flash-style attention ----------------
// QKV fused [M][3072]: Q at col 0, K at 1024, V at 2048 (+ h*64).
// Output ctx bf16 [M][1024].
__global__ __launch_bounds__(256)
void attn_tiled(const float* __restrict__ QKV, const float* __restrict__ bias,
                const int* __restrict__ mask, ushort* __restrict__ ctx) {
    const int q0 = blockIdx.x * 64;
    const int h  = blockIdx.y;
    const int b  = blockIdx.z;
    const int tid = threadIdx.x;
    const int tm = (tid >> 4) * 4;
    const int tn = (tid & 15) * 4;

    __shared__ __align__(16) float Qs[64][68];
    __shared__ __align__(16) float KVs[64][68];
    __shared__ __align__(16) float Ps[64][68];
    __shared__ float pm[4][64];
    __shared__ float rowm[64], rowl[64], rowa[64];

    const size_t head_off = (size_t)h * DHH;

    {
        const int row = tid >> 2;
        const int quarter = tid & 3;
        const float* qrow = QKV + ((size_t)(b * LL + q0 + row)) * LDQ + head_off;
        #pragma unroll
        for (int i = 0; i < 4; ++i) {
            const int d0 = quarter * 16 + i * 4;
            float4 v = *(const float4*)&qrow[d0];
            Qs[d0 + 0][row] = v.x;
            Qs[d0 + 1][row] = v.y;
            Qs[d0 + 2][row] = v.z;
            Qs[d0 + 3][row] = v.w;
        }
    }
    if (tid < 64) {
        rowm[tid] = -3.4e38f;
        rowl[tid] = 0.0f;
    }

    float acc_o[4][4] = {};
    const float* bias_base = bias + ((size_t)b * LL) * LL;
    const int* mrow = mask + b * LL;

    for (int kt = 0; kt < 16; ++kt) {
        const int k0 = kt * 64;

        {
            const int row = tid >> 2;
            const int quarter = tid & 3;
            const float* krow = QKV + ((size_t)(b * LL + k0 + row)) * LDQ + 1024 + head_off;
            #pragma unroll
            for (int i = 0; i < 4; ++i) {
                const int d0 = quarter * 16 + i * 4;
                float4 v = *(const float4*)&krow[d0];
                KVs[d0 + 0][row] = v.x;
                KVs[d0 + 1][row] = v.y;
                KVs[d0 + 2][row] = v.z;
                KVs[d0 + 3][row] = v.w;
            }
        }
        __syncthreads();

        float acc_s[4][4] = {};
        #pragma unroll
        for (int d = 0; d < 64; ++d) {
            float4 a4 = *(float4*)&Qs[d][tm];
            float4 b4 = *(float4*)&KVs[d][tn];
            float a[4] = {a4.x, a4.y, a4.z, a4.w};
            float bb[4] = {b4.x, b4.y, b4.z, b4.w};
            #pragma unroll
            for (int i = 0; i < 4; ++i)
                #pragma unroll
                for (int j = 0; j < 4; ++j)
                    acc_s[i][j] = fmaf(a[i], bb[j], acc_s[i][j]);
        }
        int4 mv = *(const int4*)&mrow[k0 + tn];
        const int mk[4] = {mv.x, mv.y, mv.z, mv.w};
        #pragma unroll
        for (int i = 0; i < 4; ++i) {
            const int q = q0 + tm + i;
            float4 bias4 = *(const float4*)&bias_base[(size_t)q * LL + k0 + tn];
            float bb[4] = {bias4.x, bias4.y, bias4.z, bias4.w};
            #pragma unroll
            for (int j = 0; j < 4; ++j) {
                float sc = acc_s[i][j] * 0.125f * bb[j];
                acc_s[i][j] = (mk[j] == 0) ? -10000.0f : sc;
            }
        }
        __syncthreads();

        #pragma unroll
        for (int i = 0; i < 4; ++i)
            #pragma unroll
            for (int j = 0; j < 4; ++j)
                Ps[tn + j][tm + i] = acc_s[i][j];
        {
            const int row = tid >> 2;
            const int quarter = tid & 3;
            const float* vrow = QKV + ((size_t)(b * LL + k0 + row)) * LDQ + 2048 + head_off;
            #pragma unroll
            for (int i = 0; i < 4; ++i) {
                const int d0 = quarter * 16 + i * 4;
                *(float4*)&KVs[row][d0] = *(const float4*)&vrow[d0];
            }
        }
        __syncthreads();

        const int qi = tid & 63;
        const int grp = tid >> 6;
        {
            float m = -3.4e38f;
            #pragma unroll
            for (int k = 0; k < 16; ++k) m = fmaxf(m, Ps[grp * 16 + k][qi]);
            pm[grp][qi] = m;
        }
        __syncthreads();
        if (tid < 64) {
            float mt = fmaxf(fmaxf(pm[0][tid], pm[1][tid]), fmaxf(pm[2][tid], pm[3][tid]));
            float mo = rowm[tid];
            float mn = fmaxf(mo, mt);
            rowm[tid] = mn;
            rowa[tid] = __expf(mo - mn);
        }
        __syncthreads();
        {
            float lsum = 0.0f;
            const float mn = rowm[qi];
            #pragma unroll
            for (int k = 0; k < 16; ++k) {
                float p = __expf(Ps[grp * 16 + k][qi] - mn);
                Ps[grp * 16 + k][qi] = p;
                lsum += p;
            }
            pm[grp][qi] = lsum;
        }
        __syncthreads();
        if (tid < 64)
            rowl[tid] = rowl[tid] * rowa[tid] + pm[0][tid] + pm[1][tid] + pm[2][tid] + pm[3][tid];

        float al[4];
        #pragma unroll
        for (int i = 0; i < 4; ++i) al[i] = rowa[tm + i];
        #pragma unroll
        for (int i = 0; i < 4; ++i)
            #pragma unroll
            for (int j = 0; j < 4; ++j)
                acc_o[i][j] *= al[i];

        #pragma unroll
        for (int k = 0; k < 64; ++k) {
            float4 a4 = *(float4*)&Ps[k][tm];
            float4 b4 = *(float4*)&KVs[k][tn];
            float a[4] = {a4.x, a4.y, a4.z, a4.w};
            float bb[4] = {b4.x, b4.y, b4.z, b4.w};
            #pragma unroll
            for (int i = 0; i < 4; ++i)
                #pragma unroll
                for (int j = 0; j < 4; ++j)
                    acc_o[i][j] = fmaf(a[i], bb[j], acc_o[i][j]);
        }
        __syncthreads();
    }

    #pragma unroll
    for (int i = 0; i < 4; ++i) {
        const float inv = 1.0f / rowl[tm + i];
        ushort4 o;
        o.x = f2bf(acc_o[i][0] * inv);
        o.y = f2bf(acc_o[i][1] * inv);
        o.z = f2bf(acc_o[i][2] * inv);
        o.w = f2bf(acc_o[i][3] * inv);
        *(ushort4*)&ctx[((size_t)(b * LL + q0 + tm + i)) * DD + head_off + tn] = o;
    }
}

// ---------------- residual add + LayerNorm (optional bf16 copy) ------------
__global__ __launch_bounds__(256)
void add_ln_kernel(const float* __restrict__ a, const float* __restrict__ bres,
                   const float* __restrict__ gamma, const float* __restrict__ beta,
                   float* __restrict__ out, ushort* __restrict__ outb) {
    const int row = blockIdx.x;
    const int tid = threadIdx.x;
    __shared__ float red[256];

    const size_t base = (size_t)row * DD;
    float v[4];
    float sum = 0.0f;
    #pragma unroll
    for (int i = 0; i < 4; ++i) {
        const int col = tid + i * 256;
        v[i] = a[base + col] + bres[base + col];
        sum += v[i];
    }
    const float mean = block_reduce_sum(sum, red, tid) * (1.0f / 1024.0f);
    float vs = 0.0f;
    #pragma unroll
    for (int i = 0; i < 4; ++i) {
        const float dlt = v[i] - mean;
        vs += dlt * dlt;
    }
    const float var = block_reduce_sum(vs, red, tid) * (1.0f / 1024.0f);
    const float rstd = rsqrtf(var + 1e-12f);
    #pragma unroll
    for (int i = 0; i < 4; ++i) {
        const int col = tid + i * 256;
        const float o = gamma[col] * (v[i] - mean) * rstd + beta[col];
        out[base + col] = o;
        if (outb) outb[base + col] = f2bf(o);
    }
}

extern "C" void kernel_launch(void* const* d_in, const int* in_sizes, int n_in,
                              void* d_out, int out_size, void* d_ws, size_t ws_size,
                              hipStream_t stream) {
    const float* x         = (const float*)d_in[0];
    const float* attn_bias = (const float*)d_in[1];
    const int*   src_mask  = (const int*)  d_in[2];
    const float* wq = (const float*)d_in[3];
    const float* bq = (const float*)d_in[4];
    const float* wk = (const float*)d_in[5];
    const float* bk = (const float*)d_in[6];
    const float* wv = (const float*)d_in[7];
    const float* bv = (const float*)d_in[8];
    const float* wo = (const float*)d_in[9];
    const float* bo = (const float*)d_in[10];
    const float* gamma1 = (const float*)d_in[11];
    const float* beta1  = (const float*)d_in[12];
    const float* w1 = (const float*)d_in[13];
    const float* b1 = (const float*)d_in[14];
    const float* w2 = (const float*)d_in[15];
    const float* b2 = (const float*)d_in[16];
    const float* gamma2 = (const float*)d_in[17];
    const float* beta2  = (const float*)d_in[18];
    float* out = (float*)d_out;

    // workspace arena (96 MB, time-multiplexed)
    const size_t MB = 1024 * 1024;
    char* W = (char*)d_ws;
    float*  QKV   = (float*) (W + 0);        // [4096][3072] fp32, steps 3-4
    ushort* W1T   = (ushort*)(W + 32 * MB);  // [4096][1024] bf16 (after QKV dead)
    ushort* W2T   = (ushort*)(W + 40 * MB);  // [1024][4096] bf16
    ushort* F1b   = (ushort*)(W + 0);        // [4096][4096] bf16 (after QKV dead)
    ushort* XBCH  = (ushort*)(W + 48 * MB);  // 8 MB multiplexed: xb -> Cxb -> Hbb
    ushort* WQKVT = (ushort*)(W + 56 * MB);  // [3072][1024] bf16
    ushort* WOT   = (ushort*)(W + 56 * MB);  // [1024][1024] bf16 (after WQKVT dead)
    float*  bqkv  = (float*) (W + 62 * MB);  // [3072] fp32
    float*  Ao    = (float*) (W + 64 * MB);  // [4096][1024] fp32
    float*  F2    = (float*) (W + 64 * MB);  // [4096][1024] fp32 (after Ao dead)
    float*  Hb    = (float*) (W + 80 * MB);  // [4096][1024] fp32

    dim3 blk(256);

    // 1. cast x -> bf16
    cast_bf16<<<dim3(4096), blk, 0, stream>>>(x, XBCH);
    // 2. weight transposes for QKV + bias concat
    transpose_cast<<<dim3(32, 32), blk, 0, stream>>>(wq, WQKVT, DD, DD);
    transpose_cast<<<dim3(32, 32), blk, 0, stream>>>(wk, WQKVT + 1024 * 1024, DD, DD);
    transpose_cast<<<dim3(32, 32), blk, 0, stream>>>(wv, WQKVT + 2048 * 1024, DD, DD);
    concat3<<<dim3(12), blk, 0, stream>>>(bq, bk, bv, bqkv);
    // 3. fused QKV projection: [4096,3072] = xb @ WQKVT^T
    gemm_bf16<<<dim3(24, 32), blk, 0, stream>>>(XBCH, WQKVT, bqkv, QKV,
                                                MM, LDQ, DD, 0, 0);
    // 4. attention -> ctx bf16 (overwrites xb region)
    attn_tiled<<<dim3(16, HH, BB), blk, 0, stream>>>(QKV, attn_bias, src_mask, XBCH);
    // 5-6. output projection
    transpose_cast<<<dim3(32, 32), blk, 0, stream>>>(wo, WOT, DD, DD);
    gemm_bf16<<<dim3(8, 32), blk, 0, stream>>>(XBCH, WOT, bo, Ao,
                                               MM, DD, DD, 0, 0);
    // 7. h = LN(x + attn_out), fp32 + bf16
    add_ln_kernel<<<dim3(MM), blk, 0, stream>>>(Ao, x, gamma1, beta1, Hb, XBCH);
    // 8-9. FFN1 (relu, bf16 out)
    transpose_cast<<<dim3(128, 32), blk, 0, stream>>>(w1, W1T, DD, FFF);
    gemm_bf16<<<dim3(32, 32), blk, 0, stream>>>(XBCH, W1T, b1, F1b,
                                                MM, FFF, DD, 1, 1);
    // 10-11. FFN2 (fp32 out)
    transpose_cast<<<dim3(32, 128), blk, 0, stream>>>(w2, W2T, FFF, DD);
    gemm_bf16<<<dim3(8, 32), blk, 0, stream>>>(F1b, W2T, b2, F2,
                                               MM, DD, FFF, 0, 0);
    // 12. out = LN(h + ffn)
    add_ln_kernel<<<dim3(MM), blk, 0, stream>>>(F2, Hb, gamma2, beta2, out, nullptr);
}

// Round 5
// 514.398 us; speedup vs baseline: 9.7493x; 1.5587x over previous
//
#include <hip/hip_runtime.h>
#include <hip/hip_bf16.h>
#include <math.h>

// Problem constants
#define BB 4
#define LL 1024
#define DD 1024
#define HH 16
#define DHH 64
#define FFF 4096
#define MM (BB*LL)     // 4096 rows
#define LDQ 3072       // fused QKV row stride

typedef __attribute__((ext_vector_type(8))) short short8;
typedef __attribute__((ext_vector_type(4))) float f32x4;

__device__ __forceinline__ ushort f2bf(float f) {
    __hip_bfloat16 h = __float2bfloat16(f);
    return *(ushort*)&h;
}

// ---------------- block reduction helper ----------------
__device__ __forceinline__ float block_reduce_sum(float v, float* red, int tid) {
    red[tid] = v;
    __syncthreads();
    for (int off = 128; off > 0; off >>= 1) {
        if (tid < off) red[tid] += red[tid + off];
        __syncthreads();
    }
    float r = red[0];
    __syncthreads();
    return r;
}

// ---------------- elementwise cast fp32 -> bf16 ----------------
__global__ __launch_bounds__(256)
void cast_bf16(const float* __restrict__ in, ushort* __restrict__ out) {
    const int i = blockIdx.x * 256 + threadIdx.x;
    float4 v = ((const float4*)in)[i];
    ushort4 o;
    o.x = f2bf(v.x); o.y = f2bf(v.y); o.z = f2bf(v.z); o.w = f2bf(v.w);
    ((ushort4*)out)[i] = o;
}

// ---------------- tiled transpose + cast: W[K][N] fp32 -> WT[N][K] bf16 ----
__global__ __launch_bounds__(256)
void transpose_cast(const float* __restrict__ W, ushort* __restrict__ WT,
                    int K, int N) {
    __shared__ float tile[32][33];
    const int n0 = blockIdx.x * 32, k0 = blockIdx.y * 32;
    const int t = threadIdx.x;
    const int r = t >> 3, c4 = (t & 7) * 4;
    float4 v = *(const float4*)&W[(size_t)(k0 + r) * N + n0 + c4];
    tile[r][c4 + 0] = v.x; tile[r][c4 + 1] = v.y;
    tile[r][c4 + 2] = v.z; tile[r][c4 + 3] = v.w;
    __syncthreads();
    ushort4 o;
    o.x = f2bf(tile[c4 + 0][r]);
    o.y = f2bf(tile[c4 + 1][r]);
    o.z = f2bf(tile[c4 + 2][r]);
    o.w = f2bf(tile[c4 + 3][r]);
    *(ushort4*)&WT[(size_t)(n0 + r) * K + k0 + c4] = o;
}

// ---------------- concat 3 bias vectors of 1024 ----------------
__global__ __launch_bounds__(256)
void concat3(const float* __restrict__ a, const float* __restrict__ b,
             const float* __restrict__ c, float* __restrict__ o) {
    const int i = blockIdx.x * 256 + threadIdx.x;
    o[i] = (i < 1024) ? a[i] : ((i < 2048) ? b[i - 1024] : c[i - 2048]);
}

// ---------------- bf16 MFMA GEMM (m97 structure), templated BN ------------
// C[M,N] = A[M,K] @ Bt[N,K]^T + bias. Options:
//  relu, obf16 (bf16 out), qlim (cols < qlim scaled by 0.125),
//  vn0: cols >= vn0 are written TRANSPOSED-bf16 to Vt[(m>>10)*1024 + (n-vn0)][m&1023]
template<int BN>
__global__ __launch_bounds__(256)
void gemm_bf16(const ushort* __restrict__ A, const ushort* __restrict__ Bt,
               const float* __restrict__ bias, void* __restrict__ C,
               ushort* __restrict__ Vt, int vn0,
               int M, int N, int K, int relu, int obf16, int qlim) {
    constexpr int JF = BN / 32;        // j-frags per wave
    __shared__ ushort Als[128 * 32];
    __shared__ ushort Bls[BN * 32];

    const int bm = blockIdx.y * 128;
    const int bn = blockIdx.x * BN;
    const int t = threadIdx.x;
    const int lane = t & 63;
    const int w = t >> 6;
    const int wm = (w >> 1) * 64;
    const int wn = (w & 1) * (BN / 2);
    const int fm = lane & 15;
    const int kg = lane >> 4;

    f32x4 acc[4][JF] = {};

    for (int k0 = 0; k0 < K; k0 += 32) {
        #pragma unroll
        for (int j = 0; j < 2; ++j) {
            const int chunk = j * 256 + t;
            const int row = chunk >> 2, kc = chunk & 3;
            const ushort* ga = A + (size_t)(bm + row) * K + k0 + kc * 8;
            __builtin_amdgcn_global_load_lds(
                (const __attribute__((address_space(1))) void*)ga,
                (__attribute__((address_space(3))) void*)(Als + chunk * 8), 16, 0, 0);
        }
        #pragma unroll
        for (int j = 0; j < BN / 64; ++j) {
            const int chunk = j * 256 + t;
            const int row = chunk >> 2, kc = chunk & 3;
            const ushort* gb = Bt + (size_t)(bn + row) * K + k0 + kc * 8;
            __builtin_amdgcn_global_load_lds(
                (const __attribute__((address_space(1))) void*)gb,
                (__attribute__((address_space(3))) void*)(Bls + chunk * 8), 16, 0, 0);
        }
        __syncthreads();

        short8 af[4], bfr[JF];
        #pragma unroll
        for (int i = 0; i < 4; ++i)
            af[i] = *(const short8*)&Als[(wm + i * 16 + fm) * 32 + kg * 8];
        #pragma unroll
        for (int j = 0; j < JF; ++j)
            bfr[j] = *(const short8*)&Bls[(wn + j * 16 + fm) * 32 + kg * 8];
        #pragma unroll
        for (int i = 0; i < 4; ++i)
            #pragma unroll
            for (int j = 0; j < JF; ++j)
                acc[i][j] = __builtin_amdgcn_mfma_f32_16x16x32_bf16(
                    af[i], bfr[j], acc[i][j], 0, 0, 0);
        __syncthreads();
    }

    const int orow0 = (lane >> 4) * 4;
    const int ocol = lane & 15;
    #pragma unroll
    for (int j = 0; j < JF; ++j) {
        const int n = bn + wn + j * 16 + ocol;
        const float bv = bias[n];
        const bool isV = (bn + wn + j * 16) >= vn0;   // frag-uniform
        #pragma unroll
        for (int i = 0; i < 4; ++i) {
            const int m0 = bm + wm + i * 16 + orow0;
            if (isV) {
                ushort4 o;
                float v0 = acc[i][j][0] + bv, v1 = acc[i][j][1] + bv;
                float v2 = acc[i][j][2] + bv, v3 = acc[i][j][3] + bv;
                o.x = f2bf(v0); o.y = f2bf(v1); o.z = f2bf(v2); o.w = f2bf(v3);
                *(ushort4*)&Vt[((size_t)((m0 >> 10) << 10) + (n - vn0)) * 1024 + (m0 & 1023)] = o;
            } else {
                #pragma unroll
                for (int r = 0; r < 4; ++r) {
                    const int m = m0 + r;
                    float v = acc[i][j][r] + bv;
                    if (relu) v = fmaxf(v, 0.0f);
                    if (n < qlim) v *= 0.125f;
                    if (obf16)
                        ((ushort*)C)[(size_t)m * N + n] = f2bf(v);
                    else
                        ((float*)C)[(size_t)m * N + n] = v;
                }
            }
        }
    }
}

// ---------------- MFMA flash attention ----------------
// Block = (b, h, 64-q-tile); 4 waves, wave w owns q-rows w*16..w*16+15.
// Q pre-scaled by 0.125 in the QKV GEMM. V read from Vt[b,h,d,k].
__global__ __launch_bounds__(256)
void attn_mfma(const ushort* __restrict__ QKVb, const ushort* __restrict__ Vt,
               const float* __restrict__ bias, const int* __restrict__ mask,
               ushort* __restrict__ ctx) {
    const int q0 = blockIdx.x * 64;
    const int h = blockIdx.y;
    const int b = blockIdx.z;
    const int t = threadIdx.x;
    const int lane = t & 63;
    const int w = t >> 6;
    const int g = lane >> 4;     // quad
    const int c = lane & 15;

    __shared__ ushort Qs[64 * 72];
    __shared__ ushort Ks[64 * 72];
    __shared__ ushort Vs[64 * 72];
    __shared__ ushort Ps[4][16 * 72];

    // ---- stage Q tile (64x64 bf16, padded rows) ----
    #pragma unroll
    for (int i = 0; i < 2; ++i) {
        const int chunk = i * 256 + t;
        const int row = chunk >> 3, c8 = (chunk & 7) * 8;
        *(short8*)&Qs[row * 72 + c8] =
            *(const short8*)(QKVb + ((size_t)(b * LL + q0 + row)) * LDQ + h * DHH + c8);
    }
    __syncthreads();

    // preload Q A-frags (loop-invariant): m=lane&15 -> q=w*16+c, k=g*8+j
    short8 aq0 = *(const short8*)&Qs[(w * 16 + c) * 72 + g * 8];
    short8 aq1 = *(const short8*)&Qs[(w * 16 + c) * 72 + g * 8 + 32];

    float m_pr[4] = {-3.4e38f, -3.4e38f, -3.4e38f, -3.4e38f};
    float l_run[4] = {0.f, 0.f, 0.f, 0.f};
    f32x4 acc_o[4] = {};

    const float* bias_r[4];
    #pragma unroll
    for (int r = 0; r < 4; ++r)
        bias_r[r] = bias + ((size_t)(b * LL + q0 + w * 16 + 4 * g + r)) * LL + c;
    const int* mrow = mask + b * LL;

    for (int kt = 0; kt < 16; ++kt) {
        const int k0 = kt * 64;

        // ---- stage K tile + V^T tile ----
        #pragma unroll
        for (int i = 0; i < 2; ++i) {
            const int chunk = i * 256 + t;
            const int row = chunk >> 3, c8 = (chunk & 7) * 8;
            *(short8*)&Ks[row * 72 + c8] =
                *(const short8*)(QKVb + ((size_t)(b * LL + k0 + row)) * LDQ + 1024 + h * DHH + c8);
            *(short8*)&Vs[row * 72 + c8] =
                *(const short8*)(Vt + ((size_t)((b * HH + h) * DHH + row)) * LL + k0 + c8);
        }
        __syncthreads();

        // ---- S = Q.K^T (MFMA, fp32 acc, C layout) ----
        f32x4 accs[4] = {};
        #pragma unroll
        for (int j = 0; j < 4; ++j) {
            short8 bk0 = *(const short8*)&Ks[(j * 16 + c) * 72 + g * 8];
            short8 bk1 = *(const short8*)&Ks[(j * 16 + c) * 72 + g * 8 + 32];
            accs[j] = __builtin_amdgcn_mfma_f32_16x16x32_bf16(aq0, bk0, accs[j], 0, 0, 0);
            accs[j] = __builtin_amdgcn_mfma_f32_16x16x32_bf16(aq1, bk1, accs[j], 0, 0, 0);
        }

        // ---- bias * mask ----
        int mk[4];
        #pragma unroll
        for (int j = 0; j < 4; ++j) mk[j] = mrow[k0 + j * 16 + c];
        float sc[4][4];
        #pragma unroll
        for (int j = 0; j < 4; ++j)
            #pragma unroll
            for (int r = 0; r < 4; ++r) {
                float v = accs[j][r] * bias_r[r][k0 + j * 16];
                sc[j][r] = (mk[j] == 0) ? -10000.0f : v;
            }

        // ---- online softmax: row max over 16 lanes ----
        float mt[4];
        #pragma unroll
        for (int r = 0; r < 4; ++r)
            mt[r] = fmaxf(fmaxf(sc[0][r], sc[1][r]), fmaxf(sc[2][r], sc[3][r]));
        #pragma unroll
        for (int d = 1; d < 16; d <<= 1)
            #pragma unroll
            for (int r = 0; r < 4; ++r)
                mt[r] = fmaxf(mt[r], __shfl_xor(mt[r], d));

        float al[4], lt[4];
        #pragma unroll
        for (int r = 0; r < 4; ++r) {
            float mn = fmaxf(m_pr[r], mt[r]);
            al[r] = __expf(m_pr[r] - mn);
            m_pr[r] = mn;
            lt[r] = 0.0f;
        }

        // ---- P = exp(S - m), write bf16 to Ps (A-layout rows) ----
        #pragma unroll
        for (int j = 0; j < 4; ++j)
            #pragma unroll
            for (int r = 0; r < 4; ++r) {
                float p = __expf(sc[j][r] - m_pr[r]);
                lt[r] += p;
                Ps[w][(4 * g + r) * 72 + j * 16 + c] = f2bf(p);
            }
        #pragma unroll
        for (int d = 1; d < 16; d <<= 1)
            #pragma unroll
            for (int r = 0; r < 4; ++r)
                lt[r] += __shfl_xor(lt[r], d);
        #pragma unroll
        for (int r = 0; r < 4; ++r)
            l_run[r] = l_run[r] * al[r] + lt[r];

        // ---- rescale O ----
        #pragma unroll
        for (int j = 0; j < 4; ++j)
            #pragma unroll
            for (int r = 0; r < 4; ++r)
                acc_o[j][r] *= al[r];

        // ---- O += P.V (A from Ps, B from Vs) ----
        #pragma unroll
        for (int ks = 0; ks < 2; ++ks) {
            short8 ap = *(const short8*)&Ps[w][c * 72 + ks * 32 + g * 8];
            #pragma unroll
            for (int j = 0; j < 4; ++j) {
                short8 bv = *(const short8*)&Vs[(j * 16 + c) * 72 + ks * 32 + g * 8];
                acc_o[j] = __builtin_amdgcn_mfma_f32_16x16x32_bf16(ap, bv, acc_o[j], 0, 0, 0);
            }
        }
        __syncthreads();
    }

    // ---- epilogue: normalize, store bf16 ctx ----
    #pragma unroll
    for (int r = 0; r < 4; ++r) {
        const float inv = 1.0f / l_run[r];
        #pragma unroll
        for (int j = 0; j < 4; ++j)
            ctx[((size_t)(b * LL + q0 + w * 16 + 4 * g + r)) * DD + h * DHH + j * 16 + c] =
                f2bf(acc_o[j][r] * inv);
    }
}

// ---------------- residual add + LayerNorm (optional bf16 copy) ------------
__global__ __launch_bounds__(256)
void add_ln_kernel(const float* __restrict__ a, const float* __restrict__ bres,
                   const float* __restrict__ gamma, const float* __restrict__ beta,
                   float* __restrict__ out, ushort* __restrict__ outb) {
    const int row = blockIdx.x;
    const int tid = threadIdx.x;
    __shared__ float red[256];

    const size_t base = (size_t)row * DD;
    float v[4];
    float sum = 0.0f;
    #pragma unroll
    for (int i = 0; i < 4; ++i) {
        const int col = tid + i * 256;
        v[i] = a[base + col] + bres[base + col];
        sum += v[i];
    }
    const float mean = block_reduce_sum(sum, red, tid) * (1.0f / 1024.0f);
    float vs = 0.0f;
    #pragma unroll
    for (int i = 0; i < 4; ++i) {
        const float dlt = v[i] - mean;
        vs += dlt * dlt;
    }
    const float var = block_reduce_sum(vs, red, tid) * (1.0f / 1024.0f);
    const float rstd = rsqrtf(var + 1e-12f);
    #pragma unroll
    for (int i = 0; i < 4; ++i) {
        const int col = tid + i * 256;
        const float o = gamma[col] * (v[i] - mean) * rstd + beta[col];
        out[base + col] = o;
        if (outb) outb[base + col] = f2bf(o);
    }
}

extern "C" void kernel_launch(void* const* d_in, const int* in_sizes, int n_in,
                              void* d_out, int out_size, void* d_ws, size_t ws_size,
                              hipStream_t stream) {
    const float* x         = (const float*)d_in[0];
    const float* attn_bias = (const float*)d_in[1];
    const int*   src_mask  = (const int*)  d_in[2];
    const float* wq = (const float*)d_in[3];
    const float* bq = (const float*)d_in[4];
    const float* wk = (const float*)d_in[5];
    const float* bk = (const float*)d_in[6];
    const float* wv = (const float*)d_in[7];
    const float* bv = (const float*)d_in[8];
    const float* wo = (const float*)d_in[9];
    const float* bo = (const float*)d_in[10];
    const float* gamma1 = (const float*)d_in[11];
    const float* beta1  = (const float*)d_in[12];
    const float* w1 = (const float*)d_in[13];
    const float* b1 = (const float*)d_in[14];
    const float* w2 = (const float*)d_in[15];
    const float* b2 = (const float*)d_in[16];
    const float* gamma2 = (const float*)d_in[17];
    const float* beta2  = (const float*)d_in[18];
    float* out = (float*)d_out;

    // workspace arena (96 MB, time-multiplexed)
    const size_t MB = 1024 * 1024;
    char* W = (char*)d_ws;
    ushort* xb    = (ushort*)(W + 0);        // 8 MB; dead after QKV gemm
    ushort* ctxb  = (ushort*)(W + 0);        // 8 MB (attn output)
    ushort* QKVb  = (ushort*)(W + 8 * MB);   // 24 MB bf16 [4096][3072]; dead after attn
    ushort* F1b   = (ushort*)(W + 8 * MB);   // 32 MB bf16 (FFN1 out)
    ushort* Vt    = (ushort*)(W + 40 * MB);  // 8 MB bf16 [b*16+h][64 d][1024 k]
    ushort* W1T   = (ushort*)(W + 40 * MB);  // 8 MB (transpose after attn)
    ushort* WQKVT = (ushort*)(W + 48 * MB);  // 6 MB; dead after QKV gemm
    ushort* WOT   = (ushort*)(W + 48 * MB);  // 2 MB
    ushort* Hbb   = (ushort*)(W + 54 * MB);  // 8 MB bf16 h; dead after FFN1
    ushort* W2T   = (ushort*)(W + 54 * MB);  // 8 MB (transpose after FFN1)
    float*  bqkv  = (float*) (W + 62 * MB);  // 12 KB
    float*  Ao    = (float*) (W + 64 * MB);  // 16 MB fp32; dead after LN1
    float*  F2    = (float*) (W + 64 * MB);  // 16 MB fp32
    float*  Hb    = (float*) (W + 80 * MB);  // 16 MB fp32 (live to end)

    dim3 blk(256);

    // 1. cast x -> bf16
    cast_bf16<<<dim3(4096), blk, 0, stream>>>(x, xb);
    // 2. QKV weight transposes + bias concat
    transpose_cast<<<dim3(32, 32), blk, 0, stream>>>(wq, WQKVT, DD, DD);
    transpose_cast<<<dim3(32, 32), blk, 0, stream>>>(wk, WQKVT + 1024 * 1024, DD, DD);
    transpose_cast<<<dim3(32, 32), blk, 0, stream>>>(wv, WQKVT + 2048 * 1024, DD, DD);
    concat3<<<dim3(12), blk, 0, stream>>>(bq, bk, bv, bqkv);
    // 3. fused QKV projection (bf16 out; Q scaled 0.125; V -> Vt transposed)
    gemm_bf16<128><<<dim3(24, 32), blk, 0, stream>>>(xb, WQKVT, bqkv, QKVb,
                                                     Vt, 2048, MM, LDQ, DD, 0, 1, 1024);
    // 4. MFMA flash attention -> ctx bf16
    attn_mfma<<<dim3(16, HH, BB), blk, 0, stream>>>(QKVb, Vt, attn_bias, src_mask, ctxb);
    // 5. WO transpose + output projection (fp32 out)
    transpose_cast<<<dim3(32, 32), blk, 0, stream>>>(wo, WOT, DD, DD);
    gemm_bf16<64><<<dim3(16, 32), blk, 0, stream>>>(ctxb, WOT, bo, Ao,
                                                    Vt, 1 << 30, MM, DD, DD, 0, 0, 0);
    // 6. h = LN(x + attn_out), fp32 + bf16
    add_ln_kernel<<<dim3(MM), blk, 0, stream>>>(Ao, x, gamma1, beta1, Hb, Hbb);
    // 7. FFN1 (relu, bf16 out)
    transpose_cast<<<dim3(128, 32), blk, 0, stream>>>(w1, W1T, DD, FFF);
    gemm_bf16<128><<<dim3(32, 32), blk, 0, stream>>>(Hbb, W1T, b1, F1b,
                                                     Vt, 1 << 30, MM, FFF, DD, 1, 1, 0);
    // 8. FFN2 (fp32 out)
    transpose_cast<<<dim3(32, 128), blk, 0, stream>>>(w2, W2T, FFF, DD);
    gemm_bf16<64><<<dim3(16, 32), blk, 0, stream>>>(F1b, W2T, b2, F2,
                                                    Vt, 1 << 30, MM, DD, FFF, 0, 0, 0);
    // 9. out = LN(h + ffn)
    add_ln_kernel<<<dim3(MM), blk, 0, stream>>>(F2, Hb, gamma2, beta2, out, nullptr);
}

// Round 6
// 464.530 us; speedup vs baseline: 10.7959x; 1.1074x over previous
//
#include <hip/hip_runtime.h>
#include <hip/hip_bf16.h>
#include <math.h>

// Problem constants
#define BB 4
#define LL 1024
#define DD 1024
#define HH 16
#define DHH 64
#define FFF 4096
#define MM (BB*LL)     // 4096 rows
#define LDQ 3072       // fused QKV row stride

typedef __attribute__((ext_vector_type(8))) short short8;
typedef __attribute__((ext_vector_type(4))) float f32x4;

__device__ __forceinline__ ushort f2bf(float f) {
    __hip_bfloat16 h = __float2bfloat16(f);
    return *(ushort*)&h;
}
__device__ __forceinline__ float bf2f(ushort u) {
    __hip_bfloat16 h = *(__hip_bfloat16*)&u;
    return __bfloat162float(h);
}

// ---------------- block reduction helper ----------------
__device__ __forceinline__ float block_reduce_sum(float v, float* red, int tid) {
    red[tid] = v;
    __syncthreads();
    for (int off = 128; off > 0; off >>= 1) {
        if (tid < off) red[tid] += red[tid + off];
        __syncthreads();
    }
    float r = red[0];
    __syncthreads();
    return r;
}

// ---------------- elementwise cast fp32 -> bf16 ----------------
__global__ __launch_bounds__(256)
void cast_bf16(const float* __restrict__ in, ushort* __restrict__ out) {
    const int i = blockIdx.x * 256 + threadIdx.x;
    float4 v = ((const float4*)in)[i];
    ushort4 o;
    o.x = f2bf(v.x); o.y = f2bf(v.y); o.z = f2bf(v.z); o.w = f2bf(v.w);
    ((ushort4*)out)[i] = o;
}

// ---------------- tiled transpose + cast: W[K][N] fp32 -> WT[N][K] bf16 ----
__global__ __launch_bounds__(256)
void transpose_cast(const float* __restrict__ W, ushort* __restrict__ WT,
                    int K, int N) {
    __shared__ float tile[32][33];
    const int n0 = blockIdx.x * 32, k0 = blockIdx.y * 32;
    const int t = threadIdx.x;
    const int r = t >> 3, c4 = (t & 7) * 4;
    float4 v = *(const float4*)&W[(size_t)(k0 + r) * N + n0 + c4];
    tile[r][c4 + 0] = v.x; tile[r][c4 + 1] = v.y;
    tile[r][c4 + 2] = v.z; tile[r][c4 + 3] = v.w;
    __syncthreads();
    ushort4 o;
    o.x = f2bf(tile[c4 + 0][r]);
    o.y = f2bf(tile[c4 + 1][r]);
    o.z = f2bf(tile[c4 + 2][r]);
    o.w = f2bf(tile[c4 + 3][r]);
    *(ushort4*)&WT[(size_t)(n0 + r) * K + k0 + c4] = o;
}

// ---------------- concat 3 bias vectors of 1024 ----------------
__global__ __launch_bounds__(256)
void concat3(const float* __restrict__ a, const float* __restrict__ b,
             const float* __restrict__ c, float* __restrict__ o) {
    const int i = blockIdx.x * 256 + threadIdx.x;
    o[i] = (i < 1024) ? a[i] : ((i < 2048) ? b[i - 1024] : c[i - 2048]);
}

// ---------------- bf16 MFMA GEMM (m97 structure), templated BN ------------
// C[M,N] = A[M,K] @ Bt[N,K]^T + bias. Options:
//  relu, obf16 (bf16 out), qlim (cols < qlim scaled by 0.125),
//  vn0: cols >= vn0 are written TRANSPOSED-bf16 to Vt[(m>>10)*1024 + (n-vn0)][m&1023]
template<int BN>
__global__ __launch_bounds__(256)
void gemm_bf16(const ushort* __restrict__ A, const ushort* __restrict__ Bt,
               const float* __restrict__ bias, void* __restrict__ C,
               ushort* __restrict__ Vt, int vn0,
               int M, int N, int K, int relu, int obf16, int qlim) {
    constexpr int JF = BN / 32;        // j-frags per wave
    __shared__ ushort Als[128 * 32];
    __shared__ ushort Bls[BN * 32];

    const int bm = blockIdx.y * 128;
    const int bn = blockIdx.x * BN;
    const int t = threadIdx.x;
    const int lane = t & 63;
    const int w = t >> 6;
    const int wm = (w >> 1) * 64;
    const int wn = (w & 1) * (BN / 2);
    const int fm = lane & 15;
    const int kg = lane >> 4;

    f32x4 acc[4][JF] = {};

    for (int k0 = 0; k0 < K; k0 += 32) {
        #pragma unroll
        for (int j = 0; j < 2; ++j) {
            const int chunk = j * 256 + t;
            const int row = chunk >> 2, kc = chunk & 3;
            const ushort* ga = A + (size_t)(bm + row) * K + k0 + kc * 8;
            __builtin_amdgcn_global_load_lds(
                (const __attribute__((address_space(1))) void*)ga,
                (__attribute__((address_space(3))) void*)(Als + chunk * 8), 16, 0, 0);
        }
        #pragma unroll
        for (int j = 0; j < BN / 64; ++j) {
            const int chunk = j * 256 + t;
            const int row = chunk >> 2, kc = chunk & 3;
            const ushort* gb = Bt + (size_t)(bn + row) * K + k0 + kc * 8;
            __builtin_amdgcn_global_load_lds(
                (const __attribute__((address_space(1))) void*)gb,
                (__attribute__((address_space(3))) void*)(Bls + chunk * 8), 16, 0, 0);
        }
        __syncthreads();

        short8 af[4], bfr[JF];
        #pragma unroll
        for (int i = 0; i < 4; ++i)
            af[i] = *(const short8*)&Als[(wm + i * 16 + fm) * 32 + kg * 8];
        #pragma unroll
        for (int j = 0; j < JF; ++j)
            bfr[j] = *(const short8*)&Bls[(wn + j * 16 + fm) * 32 + kg * 8];
        #pragma unroll
        for (int i = 0; i < 4; ++i)
            #pragma unroll
            for (int j = 0; j < JF; ++j)
                acc[i][j] = __builtin_amdgcn_mfma_f32_16x16x32_bf16(
                    af[i], bfr[j], acc[i][j], 0, 0, 0);
        __syncthreads();
    }

    const int orow0 = (lane >> 4) * 4;
    const int ocol = lane & 15;
    #pragma unroll
    for (int j = 0; j < JF; ++j) {
        const int n = bn + wn + j * 16 + ocol;
        const float bv = bias[n];
        const bool isV = (bn + wn + j * 16) >= vn0;   // frag-uniform
        #pragma unroll
        for (int i = 0; i < 4; ++i) {
            const int m0 = bm + wm + i * 16 + orow0;
            if (isV) {
                ushort4 o;
                float v0 = acc[i][j][0] + bv, v1 = acc[i][j][1] + bv;
                float v2 = acc[i][j][2] + bv, v3 = acc[i][j][3] + bv;
                o.x = f2bf(v0); o.y = f2bf(v1); o.z = f2bf(v2); o.w = f2bf(v3);
                *(ushort4*)&Vt[((size_t)((m0 >> 10) << 10) + (n - vn0)) * 1024 + (m0 & 1023)] = o;
            } else {
                #pragma unroll
                for (int r = 0; r < 4; ++r) {
                    const int m = m0 + r;
                    float v = acc[i][j][r] + bv;
                    if (relu) v = fmaxf(v, 0.0f);
                    if (n < qlim) v *= 0.125f;
                    if (obf16)
                        ((ushort*)C)[(size_t)m * N + n] = f2bf(v);
                    else
                        ((float*)C)[(size_t)m * N + n] = v;
                }
            }
        }
    }
}

// ---------------- MFMA flash attention ----------------
// Block = (b, h, 64-q-tile); 4 waves, wave w owns q-rows w*16..w*16+15.
// Q pre-scaled by 0.125 in the QKV GEMM. V read from Vt[b,h,d,k].
// Bias (bf16) and mask staged through LDS.
__global__ __launch_bounds__(256)
void attn_mfma(const ushort* __restrict__ QKVb, const ushort* __restrict__ Vt,
               const ushort* __restrict__ biasb, const int* __restrict__ mask,
               ushort* __restrict__ ctx) {
    const int q0 = blockIdx.x * 64;
    const int h = blockIdx.y;
    const int b = blockIdx.z;
    const int t = threadIdx.x;
    const int lane = t & 63;
    const int w = t >> 6;
    const int g = lane >> 4;     // quad
    const int c = lane & 15;

    __shared__ ushort Qs[64 * 72];
    __shared__ ushort Ks[64 * 72];
    __shared__ ushort Vs[64 * 72];
    __shared__ ushort Bs[64 * 72];     // bias tile [q][k], bf16
    __shared__ ushort Ps[4][16 * 72];
    __shared__ int maskS[LL];

    // ---- stage Q tile (64x64 bf16, padded rows) + mask row (once) ----
    #pragma unroll
    for (int i = 0; i < 2; ++i) {
        const int chunk = i * 256 + t;
        const int row = chunk >> 3, c8 = (chunk & 7) * 8;
        *(short8*)&Qs[row * 72 + c8] =
            *(const short8*)(QKVb + ((size_t)(b * LL + q0 + row)) * LDQ + h * DHH + c8);
    }
    ((int4*)maskS)[t] = ((const int4*)(mask + b * LL))[t];
    __syncthreads();

    // preload Q A-frags (loop-invariant): m=lane&15 -> q=w*16+c, k=g*8+j
    short8 aq0 = *(const short8*)&Qs[(w * 16 + c) * 72 + g * 8];
    short8 aq1 = *(const short8*)&Qs[(w * 16 + c) * 72 + g * 8 + 32];

    float m_pr[4] = {-3.4e38f, -3.4e38f, -3.4e38f, -3.4e38f};
    float l_run[4] = {0.f, 0.f, 0.f, 0.f};
    f32x4 acc_o[4] = {};

    const ushort* bias_base = biasb + ((size_t)(b * LL + q0)) * LL;

    for (int kt = 0; kt < 16; ++kt) {
        const int k0 = kt * 64;

        // ---- stage K tile + V^T tile + bias tile ----
        #pragma unroll
        for (int i = 0; i < 2; ++i) {
            const int chunk = i * 256 + t;
            const int row = chunk >> 3, c8 = (chunk & 7) * 8;
            *(short8*)&Ks[row * 72 + c8] =
                *(const short8*)(QKVb + ((size_t)(b * LL + k0 + row)) * LDQ + 1024 + h * DHH + c8);
            *(short8*)&Vs[row * 72 + c8] =
                *(const short8*)(Vt + ((size_t)((b * HH + h) * DHH + row)) * LL + k0 + c8);
            *(short8*)&Bs[row * 72 + c8] =
                *(const short8*)(bias_base + (size_t)row * LL + k0 + c8);
        }
        __syncthreads();

        // ---- S = Q.K^T (MFMA, fp32 acc, C layout) ----
        f32x4 accs[4] = {};
        #pragma unroll
        for (int j = 0; j < 4; ++j) {
            short8 bk0 = *(const short8*)&Ks[(j * 16 + c) * 72 + g * 8];
            short8 bk1 = *(const short8*)&Ks[(j * 16 + c) * 72 + g * 8 + 32];
            accs[j] = __builtin_amdgcn_mfma_f32_16x16x32_bf16(aq0, bk0, accs[j], 0, 0, 0);
            accs[j] = __builtin_amdgcn_mfma_f32_16x16x32_bf16(aq1, bk1, accs[j], 0, 0, 0);
        }

        // ---- bias * mask (from LDS) ----
        int mk[4];
        #pragma unroll
        for (int j = 0; j < 4; ++j) mk[j] = maskS[k0 + j * 16 + c];
        float sc[4][4];
        #pragma unroll
        for (int j = 0; j < 4; ++j)
            #pragma unroll
            for (int r = 0; r < 4; ++r) {
                const float bw = bf2f(Bs[(w * 16 + 4 * g + r) * 72 + j * 16 + c]);
                float v = accs[j][r] * bw;
                sc[j][r] = (mk[j] == 0) ? -10000.0f : v;
            }

        // ---- online softmax: row max over 16 lanes ----
        float mt[4];
        #pragma unroll
        for (int r = 0; r < 4; ++r)
            mt[r] = fmaxf(fmaxf(sc[0][r], sc[1][r]), fmaxf(sc[2][r], sc[3][r]));
        #pragma unroll
        for (int d = 1; d < 16; d <<= 1)
            #pragma unroll
            for (int r = 0; r < 4; ++r)
                mt[r] = fmaxf(mt[r], __shfl_xor(mt[r], d));

        float al[4], lt[4];
        #pragma unroll
        for (int r = 0; r < 4; ++r) {
            float mn = fmaxf(m_pr[r], mt[r]);
            al[r] = __expf(m_pr[r] - mn);
            m_pr[r] = mn;
            lt[r] = 0.0f;
        }

        // ---- P = exp(S - m), write bf16 to Ps (A-layout rows) ----
        #pragma unroll
        for (int j = 0; j < 4; ++j)
            #pragma unroll
            for (int r = 0; r < 4; ++r) {
                float p = __expf(sc[j][r] - m_pr[r]);
                lt[r] += p;
                Ps[w][(4 * g + r) * 72 + j * 16 + c] = f2bf(p);
            }
        #pragma unroll
        for (int d = 1; d < 16; d <<= 1)
            #pragma unroll
            for (int r = 0; r < 4; ++r)
                lt[r] += __shfl_xor(lt[r], d);
        #pragma unroll
        for (int r = 0; r < 4; ++r)
            l_run[r] = l_run[r] * al[r] + lt[r];

        // ---- rescale O ----
        #pragma unroll
        for (int j = 0; j < 4; ++j)
            #pragma unroll
            for (int r = 0; r < 4; ++r)
                acc_o[j][r] *= al[r];

        // ---- O += P.V (A from Ps, B from Vs) ----
        #pragma unroll
        for (int ks = 0; ks < 2; ++ks) {
            short8 ap = *(const short8*)&Ps[w][c * 72 + ks * 32 + g * 8];
            #pragma unroll
            for (int j = 0; j < 4; ++j) {
                short8 bv = *(const short8*)&Vs[(j * 16 + c) * 72 + ks * 32 + g * 8];
                acc_o[j] = __builtin_amdgcn_mfma_f32_16x16x32_bf16(ap, bv, acc_o[j], 0, 0, 0);
            }
        }
        __syncthreads();
    }

    // ---- epilogue: normalize, store bf16 ctx ----
    #pragma unroll
    for (int r = 0; r < 4; ++r) {
        const float inv = 1.0f / l_run[r];
        #pragma unroll
        for (int j = 0; j < 4; ++j)
            ctx[((size_t)(b * LL + q0 + w * 16 + 4 * g + r)) * DD + h * DHH + j * 16 + c] =
                f2bf(acc_o[j][r] * inv);
    }
}

// ---------------- residual add + LayerNorm (optional bf16 copy) ------------
__global__ __launch_bounds__(256)
void add_ln_kernel(const float* __restrict__ a, const float* __restrict__ bres,
                   const float* __restrict__ gamma, const float* __restrict__ beta,
                   float* __restrict__ out, ushort* __restrict__ outb) {
    const int row = blockIdx.x;
    const int tid = threadIdx.x;
    __shared__ float red[256];

    const size_t base = (size_t)row * DD;
    float v[4];
    float sum = 0.0f;
    #pragma unroll
    for (int i = 0; i < 4; ++i) {
        const int col = tid + i * 256;
        v[i] = a[base + col] + bres[base + col];
        sum += v[i];
    }
    const float mean = block_reduce_sum(sum, red, tid) * (1.0f / 1024.0f);
    float vs = 0.0f;
    #pragma unroll
    for (int i = 0; i < 4; ++i) {
        const float dlt = v[i] - mean;
        vs += dlt * dlt;
    }
    const float var = block_reduce_sum(vs, red, tid) * (1.0f / 1024.0f);
    const float rstd = rsqrtf(var + 1e-12f);
    #pragma unroll
    for (int i = 0; i < 4; ++i) {
        const int col = tid + i * 256;
        const float o = gamma[col] * (v[i] - mean) * rstd + beta[col];
        out[base + col] = o;
        if (outb) outb[base + col] = f2bf(o);
    }
}

extern "C" void kernel_launch(void* const* d_in, const int* in_sizes, int n_in,
                              void* d_out, int out_size, void* d_ws, size_t ws_size,
                              hipStream_t stream) {
    const float* x         = (const float*)d_in[0];
    const float* attn_bias = (const float*)d_in[1];
    const int*   src_mask  = (const int*)  d_in[2];
    const float* wq = (const float*)d_in[3];
    const float* bq = (const float*)d_in[4];
    const float* wk = (const float*)d_in[5];
    const float* bk = (const float*)d_in[6];
    const float* wv = (const float*)d_in[7];
    const float* bv = (const float*)d_in[8];
    const float* wo = (const float*)d_in[9];
    const float* bo = (const float*)d_in[10];
    const float* gamma1 = (const float*)d_in[11];
    const float* beta1  = (const float*)d_in[12];
    const float* w1 = (const float*)d_in[13];
    const float* b1 = (const float*)d_in[14];
    const float* w2 = (const float*)d_in[15];
    const float* b2 = (const float*)d_in[16];
    const float* gamma2 = (const float*)d_in[17];
    const float* beta2  = (const float*)d_in[18];
    float* out = (float*)d_out;

    // workspace arena (96 MB, time-multiplexed)
    const size_t MB = 1024 * 1024;
    char* W = (char*)d_ws;
    ushort* xb    = (ushort*)(W + 0);        // 8 MB; dead after QKV gemm
    ushort* ctxb  = (ushort*)(W + 0);        // 8 MB (attn output)
    ushort* QKVb  = (ushort*)(W + 8 * MB);   // 24 MB bf16 [4096][3072]; dead after attn
    ushort* F1b   = (ushort*)(W + 8 * MB);   // 32 MB bf16 (FFN1 out)
    ushort* Vt    = (ushort*)(W + 40 * MB);  // 8 MB bf16 [b*16+h][64 d][1024 k]
    ushort* W1T   = (ushort*)(W + 40 * MB);  // 8 MB (transpose after attn)
    ushort* WQKVT = (ushort*)(W + 48 * MB);  // 6 MB; dead after QKV gemm
    ushort* WOT   = (ushort*)(W + 48 * MB);  // 2 MB
    ushort* Hbb   = (ushort*)(W + 54 * MB);  // 8 MB bf16 h; dead after FFN1
    ushort* W2T   = (ushort*)(W + 54 * MB);  // 8 MB (transpose after FFN1)
    float*  bqkv  = (float*) (W + 62 * MB);  // 12 KB
    ushort* biasb = (ushort*)(W + 64 * MB);  // 8.4 MB bf16 bias; dead before WO gemm
    float*  Ao    = (float*) (W + 64 * MB);  // 16 MB fp32; dead after LN1 (overwrites biasb)
    float*  F2    = (float*) (W + 64 * MB);  // 16 MB fp32
    float*  Hb    = (float*) (W + 80 * MB);  // 16 MB fp32 (live to end)

    dim3 blk(256);

    // 1. cast x -> bf16; cast attn_bias -> bf16
    cast_bf16<<<dim3(4096), blk, 0, stream>>>(x, xb);
    cast_bf16<<<dim3(4096), blk, 0, stream>>>(attn_bias, biasb);
    // 2. QKV weight transposes + bias concat
    transpose_cast<<<dim3(32, 32), blk, 0, stream>>>(wq, WQKVT, DD, DD);
    transpose_cast<<<dim3(32, 32), blk, 0, stream>>>(wk, WQKVT + 1024 * 1024, DD, DD);
    transpose_cast<<<dim3(32, 32), blk, 0, stream>>>(wv, WQKVT + 2048 * 1024, DD, DD);
    concat3<<<dim3(12), blk, 0, stream>>>(bq, bk, bv, bqkv);
    // 3. fused QKV projection (bf16 out; Q scaled 0.125; V -> Vt transposed)
    gemm_bf16<128><<<dim3(24, 32), blk, 0, stream>>>(xb, WQKVT, bqkv, QKVb,
                                                     Vt, 2048, MM, LDQ, DD, 0, 1, 1024);
    // 4. MFMA flash attention -> ctx bf16
    attn_mfma<<<dim3(16, HH, BB), blk, 0, stream>>>(QKVb, Vt, biasb, src_mask, ctxb);
    // 5. WO transpose + output projection (fp32 out)
    transpose_cast<<<dim3(32, 32), blk, 0, stream>>>(wo, WOT, DD, DD);
    gemm_bf16<64><<<dim3(16, 32), blk, 0, stream>>>(ctxb, WOT, bo, Ao,
                                                    Vt, 1 << 30, MM, DD, DD, 0, 0, 0);
    // 6. h = LN(x + attn_out), fp32 + bf16
    add_ln_kernel<<<dim3(MM), blk, 0, stream>>>(Ao, x, gamma1, beta1, Hb, Hbb);
    // 7. FFN1 (relu, bf16 out)
    transpose_cast<<<dim3(128, 32), blk, 0, stream>>>(w1, W1T, DD, FFF);
    gemm_bf16<128><<<dim3(32, 32), blk, 0, stream>>>(Hbb, W1T, b1, F1b,
                                                     Vt, 1 << 30, MM, FFF, DD, 1, 1, 0);
    // 8. FFN2 (fp32 out)
    transpose_cast<<<dim3(32, 128), blk, 0, stream>>>(w2, W2T, FFF, DD);
    gemm_bf16<64><<<dim3(16, 32), blk, 0, stream>>>(F1b, W2T, b2, F2,
                                                    Vt, 1 << 30, MM, DD, FFF, 0, 0, 0);
    // 9. out = LN(h + ffn)
    add_ln_kernel<<<dim3(MM), blk, 0, stream>>>(F2, Hb, gamma2, beta2, out, nullptr);
}

// Round 7
// 458.470 us; speedup vs baseline: 10.9386x; 1.0132x over previous
//
#include <hip/hip_runtime.h>
#include <hip/hip_bf16.h>
#include <math.h>

// Problem constants
#define BB 4
#define LL 1024
#define DD 1024
#define HH 16
#define DHH 64
#define FFF 4096
#define MM (BB*LL)     // 4096 rows
#define LDQ 3072       // fused QKV row stride

typedef __attribute__((ext_vector_type(8))) short short8;
typedef __attribute__((ext_vector_type(4))) float f32x4;

__device__ __forceinline__ ushort f2bf(float f) {
    __hip_bfloat16 h = __float2bfloat16(f);
    return *(ushort*)&h;
}
__device__ __forceinline__ float bf2f(ushort u) {
    __hip_bfloat16 h = *(__hip_bfloat16*)&u;
    return __bfloat162float(h);
}

// ---------------- block reduction helper ----------------
__device__ __forceinline__ float block_reduce_sum(float v, float* red, int tid) {
    red[tid] = v;
    __syncthreads();
    for (int off = 128; off > 0; off >>= 1) {
        if (tid < off) red[tid] += red[tid + off];
        __syncthreads();
    }
    float r = red[0];
    __syncthreads();
    return r;
}

// ---------------- elementwise cast fp32 -> bf16 ----------------
__global__ __launch_bounds__(256)
void cast_bf16(const float* __restrict__ in, ushort* __restrict__ out) {
    const int i = blockIdx.x * 256 + threadIdx.x;
    float4 v = ((const float4*)in)[i];
    ushort4 o;
    o.x = f2bf(v.x); o.y = f2bf(v.y); o.z = f2bf(v.z); o.w = f2bf(v.w);
    ((ushort4*)out)[i] = o;
}

// ---------------- tiled transpose + cast: W[K][N] fp32 -> WT[N][K] bf16 ----
__global__ __launch_bounds__(256)
void transpose_cast(const float* __restrict__ W, ushort* __restrict__ WT,
                    int K, int N) {
    __shared__ float tile[32][33];
    const int n0 = blockIdx.x * 32, k0 = blockIdx.y * 32;
    const int t = threadIdx.x;
    const int r = t >> 3, c4 = (t & 7) * 4;
    float4 v = *(const float4*)&W[(size_t)(k0 + r) * N + n0 + c4];
    tile[r][c4 + 0] = v.x; tile[r][c4 + 1] = v.y;
    tile[r][c4 + 2] = v.z; tile[r][c4 + 3] = v.w;
    __syncthreads();
    ushort4 o;
    o.x = f2bf(tile[c4 + 0][r]);
    o.y = f2bf(tile[c4 + 1][r]);
    o.z = f2bf(tile[c4 + 2][r]);
    o.w = f2bf(tile[c4 + 3][r]);
    *(ushort4*)&WT[(size_t)(n0 + r) * K + k0 + c4] = o;
}

// ---------------- concat 3 bias vectors of 1024 ----------------
__global__ __launch_bounds__(256)
void concat3(const float* __restrict__ a, const float* __restrict__ b,
             const float* __restrict__ c, float* __restrict__ o) {
    const int i = blockIdx.x * 256 + threadIdx.x;
    o[i] = (i < 1024) ? a[i] : ((i < 2048) ? b[i - 1024] : c[i - 2048]);
}

// ---------------- bf16 MFMA GEMM (m97 structure), templated BN ------------
template<int BN>
__global__ __launch_bounds__(256)
void gemm_bf16(const ushort* __restrict__ A, const ushort* __restrict__ Bt,
               const float* __restrict__ bias, void* __restrict__ C,
               ushort* __restrict__ Vt, int vn0,
               int M, int N, int K, int relu, int obf16, int qlim) {
    constexpr int JF = BN / 32;        // j-frags per wave
    __shared__ ushort Als[128 * 32];
    __shared__ ushort Bls[BN * 32];

    const int bm = blockIdx.y * 128;
    const int bn = blockIdx.x * BN;
    const int t = threadIdx.x;
    const int lane = t & 63;
    const int w = t >> 6;
    const int wm = (w >> 1) * 64;
    const int wn = (w & 1) * (BN / 2);
    const int fm = lane & 15;
    const int kg = lane >> 4;

    f32x4 acc[4][JF] = {};

    for (int k0 = 0; k0 < K; k0 += 32) {
        #pragma unroll
        for (int j = 0; j < 2; ++j) {
            const int chunk = j * 256 + t;
            const int row = chunk >> 2, kc = chunk & 3;
            const ushort* ga = A + (size_t)(bm + row) * K + k0 + kc * 8;
            __builtin_amdgcn_global_load_lds(
                (const __attribute__((address_space(1))) void*)ga,
                (__attribute__((address_space(3))) void*)(Als + chunk * 8), 16, 0, 0);
        }
        #pragma unroll
        for (int j = 0; j < BN / 64; ++j) {
            const int chunk = j * 256 + t;
            const int row = chunk >> 2, kc = chunk & 3;
            const ushort* gb = Bt + (size_t)(bn + row) * K + k0 + kc * 8;
            __builtin_amdgcn_global_load_lds(
                (const __attribute__((address_space(1))) void*)gb,
                (__attribute__((address_space(3))) void*)(Bls + chunk * 8), 16, 0, 0);
        }
        __syncthreads();

        short8 af[4], bfr[JF];
        #pragma unroll
        for (int i = 0; i < 4; ++i)
            af[i] = *(const short8*)&Als[(wm + i * 16 + fm) * 32 + kg * 8];
        #pragma unroll
        for (int j = 0; j < JF; ++j)
            bfr[j] = *(const short8*)&Bls[(wn + j * 16 + fm) * 32 + kg * 8];
        #pragma unroll
        for (int i = 0; i < 4; ++i)
            #pragma unroll
            for (int j = 0; j < JF; ++j)
                acc[i][j] = __builtin_amdgcn_mfma_f32_16x16x32_bf16(
                    af[i], bfr[j], acc[i][j], 0, 0, 0);
        __syncthreads();
    }

    const int orow0 = (lane >> 4) * 4;
    const int ocol = lane & 15;
    #pragma unroll
    for (int j = 0; j < JF; ++j) {
        const int n = bn + wn + j * 16 + ocol;
        const float bv = bias[n];
        const bool isV = (bn + wn + j * 16) >= vn0;   // frag-uniform
        #pragma unroll
        for (int i = 0; i < 4; ++i) {
            const int m0 = bm + wm + i * 16 + orow0;
            if (isV) {
                ushort4 o;
                float v0 = acc[i][j][0] + bv, v1 = acc[i][j][1] + bv;
                float v2 = acc[i][j][2] + bv, v3 = acc[i][j][3] + bv;
                o.x = f2bf(v0); o.y = f2bf(v1); o.z = f2bf(v2); o.w = f2bf(v3);
                *(ushort4*)&Vt[((size_t)((m0 >> 10) << 10) + (n - vn0)) * 1024 + (m0 & 1023)] = o;
            } else {
                #pragma unroll
                for (int r = 0; r < 4; ++r) {
                    const int m = m0 + r;
                    float v = acc[i][j][r] + bv;
                    if (relu) v = fmaxf(v, 0.0f);
                    if (n < qlim) v *= 0.125f;
                    if (obf16)
                        ((ushort*)C)[(size_t)m * N + n] = f2bf(v);
                    else
                        ((float*)C)[(size_t)m * N + n] = v;
                }
            }
        }
    }
}

// ---------------- MFMA flash attention, 128-q-tile + reg prefetch ----------
// Block = (b, h, 128-row q-tile); 4 waves; wave w owns q-rows w*32..w*32+31
// (two 16-row fragment groups p=0,1). Q pre-scaled by 0.125 in the QKV GEMM.
// V read from Vt[b,h,d,k]. Bias bf16 + mask staged through LDS. K/V/bias for
// tile kt+1 are prefetched into registers during tile kt's compute.
__global__ __launch_bounds__(256, 2)
void attn_mfma(const ushort* __restrict__ QKVb, const ushort* __restrict__ Vt,
               const ushort* __restrict__ biasb, const int* __restrict__ mask,
               ushort* __restrict__ ctx) {
    const int q0 = blockIdx.x * 128;
    const int h = blockIdx.y;
    const int b = blockIdx.z;
    const int t = threadIdx.x;
    const int lane = t & 63;
    const int w = t >> 6;
    const int g = lane >> 4;     // quad
    const int c = lane & 15;

    __shared__ ushort Qs[128 * 72];
    __shared__ ushort Ks[64 * 72];
    __shared__ ushort Vs[64 * 72];
    __shared__ ushort Bs[128 * 72];    // bias tile [q][k], bf16
    __shared__ ushort Ps[4][32 * 72];
    __shared__ int maskS[LL];

    // ---- stage Q tile (128x64 bf16) + mask row ----
    #pragma unroll
    for (int i = 0; i < 4; ++i) {
        const int chunk = i * 256 + t;
        const int row = chunk >> 3, c8 = (chunk & 7) * 8;
        *(short8*)&Qs[row * 72 + c8] =
            *(const short8*)(QKVb + ((size_t)(b * LL + q0 + row)) * LDQ + h * DHH + c8);
    }
    ((int4*)maskS)[t] = ((const int4*)(mask + b * LL))[t];

    // ---- prefetch tile kt=0 into registers ----
    short8 pk[2], pv[2], pb[4];
    #pragma unroll
    for (int i = 0; i < 2; ++i) {
        const int chunk = i * 256 + t;
        const int row = chunk >> 3, c8 = (chunk & 7) * 8;
        pk[i] = *(const short8*)(QKVb + ((size_t)(b * LL + row)) * LDQ + 1024 + h * DHH + c8);
        pv[i] = *(const short8*)(Vt + ((size_t)((b * HH + h) * DHH + row)) * LL + c8);
    }
    #pragma unroll
    for (int i = 0; i < 4; ++i) {
        const int chunk = i * 256 + t;
        const int row = chunk >> 3, c8 = (chunk & 7) * 8;
        pb[i] = *(const short8*)(biasb + ((size_t)(b * LL + q0 + row)) * LL + c8);
    }
    __syncthreads();

    // preload Q A-frags (loop-invariant)
    short8 aq[2][2];
    #pragma unroll
    for (int p = 0; p < 2; ++p) {
        aq[p][0] = *(const short8*)&Qs[(w * 32 + p * 16 + c) * 72 + g * 8];
        aq[p][1] = *(const short8*)&Qs[(w * 32 + p * 16 + c) * 72 + g * 8 + 32];
    }

    float m_pr[2][4], l_run[2][4];
    f32x4 acc_o[2][4] = {};
    #pragma unroll
    for (int p = 0; p < 2; ++p)
        #pragma unroll
        for (int r = 0; r < 4; ++r) { m_pr[p][r] = -3.4e38f; l_run[p][r] = 0.0f; }

    for (int kt = 0; kt < 16; ++kt) {
        // ---- write prefetched K/V/bias tile to LDS ----
        #pragma unroll
        for (int i = 0; i < 2; ++i) {
            const int chunk = i * 256 + t;
            const int row = chunk >> 3, c8 = (chunk & 7) * 8;
            *(short8*)&Ks[row * 72 + c8] = pk[i];
            *(short8*)&Vs[row * 72 + c8] = pv[i];
        }
        #pragma unroll
        for (int i = 0; i < 4; ++i) {
            const int chunk = i * 256 + t;
            const int row = chunk >> 3, c8 = (chunk & 7) * 8;
            *(short8*)&Bs[row * 72 + c8] = pb[i];
        }
        __syncthreads();

        // ---- prefetch tile kt+1 (lands during compute below) ----
        if (kt < 15) {
            const int k0n = (kt + 1) * 64;
            #pragma unroll
            for (int i = 0; i < 2; ++i) {
                const int chunk = i * 256 + t;
                const int row = chunk >> 3, c8 = (chunk & 7) * 8;
                pk[i] = *(const short8*)(QKVb + ((size_t)(b * LL + k0n + row)) * LDQ + 1024 + h * DHH + c8);
                pv[i] = *(const short8*)(Vt + ((size_t)((b * HH + h) * DHH + row)) * LL + k0n + c8);
            }
            #pragma unroll
            for (int i = 0; i < 4; ++i) {
                const int chunk = i * 256 + t;
                const int row = chunk >> 3, c8 = (chunk & 7) * 8;
                pb[i] = *(const short8*)(biasb + ((size_t)(b * LL + q0 + row)) * LL + k0n + c8);
            }
        }
        const int k0 = kt * 64;

        // ---- S = Q.K^T (MFMA, fp32 acc, C layout) ----
        f32x4 accs[2][4] = {};
        #pragma unroll
        for (int j = 0; j < 4; ++j) {
            short8 bk0 = *(const short8*)&Ks[(j * 16 + c) * 72 + g * 8];
            short8 bk1 = *(const short8*)&Ks[(j * 16 + c) * 72 + g * 8 + 32];
            #pragma unroll
            for (int p = 0; p < 2; ++p) {
                accs[p][j] = __builtin_amdgcn_mfma_f32_16x16x32_bf16(aq[p][0], bk0, accs[p][j], 0, 0, 0);
                accs[p][j] = __builtin_amdgcn_mfma_f32_16x16x32_bf16(aq[p][1], bk1, accs[p][j], 0, 0, 0);
            }
        }

        int mk[4];
        #pragma unroll
        for (int j = 0; j < 4; ++j) mk[j] = maskS[k0 + j * 16 + c];

        #pragma unroll
        for (int p = 0; p < 2; ++p) {
            // ---- bias * mask (from LDS) ----
            float sc[4][4];
            #pragma unroll
            for (int j = 0; j < 4; ++j)
                #pragma unroll
                for (int r = 0; r < 4; ++r) {
                    const float bw = bf2f(Bs[(w * 32 + p * 16 + 4 * g + r) * 72 + j * 16 + c]);
                    float v = accs[p][j][r] * bw;
                    sc[j][r] = (mk[j] == 0) ? -10000.0f : v;
                }

            // ---- online softmax: row max over 16 lanes ----
            float mt[4];
            #pragma unroll
            for (int r = 0; r < 4; ++r)
                mt[r] = fmaxf(fmaxf(sc[0][r], sc[1][r]), fmaxf(sc[2][r], sc[3][r]));
            #pragma unroll
            for (int d = 1; d < 16; d <<= 1)
                #pragma unroll
                for (int r = 0; r < 4; ++r)
                    mt[r] = fmaxf(mt[r], __shfl_xor(mt[r], d));

            float al[4], lt[4];
            #pragma unroll
            for (int r = 0; r < 4; ++r) {
                float mn = fmaxf(m_pr[p][r], mt[r]);
                al[r] = __expf(m_pr[p][r] - mn);
                m_pr[p][r] = mn;
                lt[r] = 0.0f;
            }

            // ---- P = exp(S - m), bf16 into Ps (A-layout rows) ----
            #pragma unroll
            for (int j = 0; j < 4; ++j)
                #pragma unroll
                for (int r = 0; r < 4; ++r) {
                    float pe = __expf(sc[j][r] - m_pr[p][r]);
                    lt[r] += pe;
                    Ps[w][(p * 16 + 4 * g + r) * 72 + j * 16 + c] = f2bf(pe);
                }
            #pragma unroll
            for (int d = 1; d < 16; d <<= 1)
                #pragma unroll
                for (int r = 0; r < 4; ++r)
                    lt[r] += __shfl_xor(lt[r], d);
            #pragma unroll
            for (int r = 0; r < 4; ++r)
                l_run[p][r] = l_run[p][r] * al[r] + lt[r];

            // ---- rescale O ----
            #pragma unroll
            for (int j = 0; j < 4; ++j)
                #pragma unroll
                for (int r = 0; r < 4; ++r)
                    acc_o[p][j][r] *= al[r];
        }

        // ---- O += P.V ----
        #pragma unroll
        for (int ks = 0; ks < 2; ++ks) {
            short8 ap[2];
            #pragma unroll
            for (int p = 0; p < 2; ++p)
                ap[p] = *(const short8*)&Ps[w][(p * 16 + c) * 72 + ks * 32 + g * 8];
            #pragma unroll
            for (int j = 0; j < 4; ++j) {
                short8 bv8 = *(const short8*)&Vs[(j * 16 + c) * 72 + ks * 32 + g * 8];
                #pragma unroll
                for (int p = 0; p < 2; ++p)
                    acc_o[p][j] = __builtin_amdgcn_mfma_f32_16x16x32_bf16(ap[p], bv8, acc_o[p][j], 0, 0, 0);
            }
        }
        __syncthreads();
    }

    // ---- epilogue: normalize, store bf16 ctx ----
    #pragma unroll
    for (int p = 0; p < 2; ++p)
        #pragma unroll
        for (int r = 0; r < 4; ++r) {
            const float inv = 1.0f / l_run[p][r];
            #pragma unroll
            for (int j = 0; j < 4; ++j)
                ctx[((size_t)(b * LL + q0 + w * 32 + p * 16 + 4 * g + r)) * DD + h * DHH + j * 16 + c] =
                    f2bf(acc_o[p][j][r] * inv);
        }
}

// ---------------- residual add + LayerNorm (optional bf16 copy) ------------
__global__ __launch_bounds__(256)
void add_ln_kernel(const float* __restrict__ a, const float* __restrict__ bres,
                   const float* __restrict__ gamma, const float* __restrict__ beta,
                   float* __restrict__ out, ushort* __restrict__ outb) {
    const int row = blockIdx.x;
    const int tid = threadIdx.x;
    __shared__ float red[256];

    const size_t base = (size_t)row * DD;
    float v[4];
    float sum = 0.0f;
    #pragma unroll
    for (int i = 0; i < 4; ++i) {
        const int col = tid + i * 256;
        v[i] = a[base + col] + bres[base + col];
        sum += v[i];
    }
    const float mean = block_reduce_sum(sum, red, tid) * (1.0f / 1024.0f);
    float vs = 0.0f;
    #pragma unroll
    for (int i = 0; i < 4; ++i) {
        const float dlt = v[i] - mean;
        vs += dlt * dlt;
    }
    const float var = block_reduce_sum(vs, red, tid) * (1.0f / 1024.0f);
    const float rstd = rsqrtf(var + 1e-12f);
    #pragma unroll
    for (int i = 0; i < 4; ++i) {
        const int col = tid + i * 256;
        const float o = gamma[col] * (v[i] - mean) * rstd + beta[col];
        out[base + col] = o;
        if (outb) outb[base + col] = f2bf(o);
    }
}

extern "C" void kernel_launch(void* const* d_in, const int* in_sizes, int n_in,
                              void* d_out, int out_size, void* d_ws, size_t ws_size,
                              hipStream_t stream) {
    const float* x         = (const float*)d_in[0];
    const float* attn_bias = (const float*)d_in[1];
    const int*   src_mask  = (const int*)  d_in[2];
    const float* wq = (const float*)d_in[3];
    const float* bq = (const float*)d_in[4];
    const float* wk = (const float*)d_in[5];
    const float* bk = (const float*)d_in[6];
    const float* wv = (const float*)d_in[7];
    const float* bv = (const float*)d_in[8];
    const float* wo = (const float*)d_in[9];
    const float* bo = (const float*)d_in[10];
    const float* gamma1 = (const float*)d_in[11];
    const float* beta1  = (const float*)d_in[12];
    const float* w1 = (const float*)d_in[13];
    const float* b1 = (const float*)d_in[14];
    const float* w2 = (const float*)d_in[15];
    const float* b2 = (const float*)d_in[16];
    const float* gamma2 = (const float*)d_in[17];
    const float* beta2  = (const float*)d_in[18];
    float* out = (float*)d_out;

    // workspace arena (96 MB, time-multiplexed)
    const size_t MB = 1024 * 1024;
    char* W = (char*)d_ws;
    ushort* xb    = (ushort*)(W + 0);        // 8 MB; dead after QKV gemm
    ushort* ctxb  = (ushort*)(W + 0);        // 8 MB (attn output)
    ushort* QKVb  = (ushort*)(W + 8 * MB);   // 24 MB bf16 [4096][3072]; dead after attn
    ushort* F1b   = (ushort*)(W + 8 * MB);   // 32 MB bf16 (FFN1 out)
    ushort* Vt    = (ushort*)(W + 40 * MB);  // 8 MB bf16 [b*16+h][64 d][1024 k]
    ushort* W1T   = (ushort*)(W + 40 * MB);  // 8 MB (transpose after attn)
    ushort* WQKVT = (ushort*)(W + 48 * MB);  // 6 MB; dead after QKV gemm
    ushort* WOT   = (ushort*)(W + 48 * MB);  // 2 MB
    ushort* Hbb   = (ushort*)(W + 54 * MB);  // 8 MB bf16 h; dead after FFN1
    ushort* W2T   = (ushort*)(W + 54 * MB);  // 8 MB (transpose after FFN1)
    float*  bqkv  = (float*) (W + 62 * MB);  // 12 KB
    ushort* biasb = (ushort*)(W + 64 * MB);  // 8.4 MB bf16 bias; dead before WO gemm
    float*  Ao    = (float*) (W + 64 * MB);  // 16 MB fp32; dead after LN1 (overwrites biasb)
    float*  F2    = (float*) (W + 64 * MB);  // 16 MB fp32
    float*  Hb    = (float*) (W + 80 * MB);  // 16 MB fp32 (live to end)

    dim3 blk(256);

    // 1. cast x -> bf16; cast attn_bias -> bf16
    cast_bf16<<<dim3(4096), blk, 0, stream>>>(x, xb);
    cast_bf16<<<dim3(4096), blk, 0, stream>>>(attn_bias, biasb);
    // 2. QKV weight transposes + bias concat
    transpose_cast<<<dim3(32, 32), blk, 0, stream>>>(wq, WQKVT, DD, DD);
    transpose_cast<<<dim3(32, 32), blk, 0, stream>>>(wk, WQKVT + 1024 * 1024, DD, DD);
    transpose_cast<<<dim3(32, 32), blk, 0, stream>>>(wv, WQKVT + 2048 * 1024, DD, DD);
    concat3<<<dim3(12), blk, 0, stream>>>(bq, bk, bv, bqkv);
    // 3. fused QKV projection (bf16 out; Q scaled 0.125; V -> Vt transposed)
    gemm_bf16<128><<<dim3(24, 32), blk, 0, stream>>>(xb, WQKVT, bqkv, QKVb,
                                                     Vt, 2048, MM, LDQ, DD, 0, 1, 1024);
    // 4. MFMA flash attention -> ctx bf16 (128-row q-tiles)
    attn_mfma<<<dim3(8, HH, BB), blk, 0, stream>>>(QKVb, Vt, biasb, src_mask, ctxb);
    // 5. WO transpose + output projection (fp32 out)
    transpose_cast<<<dim3(32, 32), blk, 0, stream>>>(wo, WOT, DD, DD);
    gemm_bf16<64><<<dim3(16, 32), blk, 0, stream>>>(ctxb, WOT, bo, Ao,
                                                    Vt, 1 << 30, MM, DD, DD, 0, 0, 0);
    // 6. h = LN(x + attn_out), fp32 + bf16
    add_ln_kernel<<<dim3(MM), blk, 0, stream>>>(Ao, x, gamma1, beta1, Hb, Hbb);
    // 7. FFN1 (relu, bf16 out)
    transpose_cast<<<dim3(128, 32), blk, 0, stream>>>(w1, W1T, DD, FFF);
    gemm_bf16<128><<<dim3(32, 32), blk, 0, stream>>>(Hbb, W1T, b1, F1b,
                                                     Vt, 1 << 30, MM, FFF, DD, 1, 1, 0);
    // 8. FFN2 (fp32 out)
    transpose_cast<<<dim3(32, 128), blk, 0, stream>>>(w2, W2T, FFF, DD);
    gemm_bf16<64><<<dim3(16, 32), blk, 0, stream>>>(F1b, W2T, b2, F2,
                                                    Vt, 1 << 30, MM, DD, FFF, 0, 0, 0);
    // 9. out = LN(h + ffn)
    add_ln_kernel<<<dim3(MM), blk, 0, stream>>>(F2, Hb, gamma2, beta2, out, nullptr);
}

// Round 8
// 419.820 us; speedup vs baseline: 11.9457x; 1.0921x over previous
//
#include <hip/hip_runtime.h>
#include <hip/hip_bf16.h>
#include <math.h>

// Problem constants
#define BB 4
#define LL 1024
#define DD 1024
#define HH 16
#define DHH 64
#define FFF 4096
#define MM (BB*LL)     // 4096 rows
#define LDQ 3072       // fused QKV row stride

typedef __attribute__((ext_vector_type(8))) short short8;
typedef __attribute__((ext_vector_type(4))) float f32x4;

__device__ __forceinline__ ushort f2bf(float f) {
    __hip_bfloat16 h = __float2bfloat16(f);
    return *(ushort*)&h;
}
__device__ __forceinline__ float bf2f(ushort u) {
    __hip_bfloat16 h = *(__hip_bfloat16*)&u;
    return __bfloat162float(h);
}

// ---------------- block reduction helper ----------------
__device__ __forceinline__ float block_reduce_sum(float v, float* red, int tid) {
    red[tid] = v;
    __syncthreads();
    for (int off = 128; off > 0; off >>= 1) {
        if (tid < off) red[tid] += red[tid + off];
        __syncthreads();
    }
    float r = red[0];
    __syncthreads();
    return r;
}

// ---------------- elementwise cast fp32 -> bf16 ----------------
__global__ __launch_bounds__(256)
void cast_bf16(const float* __restrict__ in, ushort* __restrict__ out) {
    const int i = blockIdx.x * 256 + threadIdx.x;
    float4 v = ((const float4*)in)[i];
    ushort4 o;
    o.x = f2bf(v.x); o.y = f2bf(v.y); o.z = f2bf(v.z); o.w = f2bf(v.w);
    ((ushort4*)out)[i] = o;
}

// ---------------- tiled transpose + cast: W[K][N] fp32 -> WT[N][K] bf16 ----
__global__ __launch_bounds__(256)
void transpose_cast(const float* __restrict__ W, ushort* __restrict__ WT,
                    int K, int N) {
    __shared__ float tile[32][33];
    const int n0 = blockIdx.x * 32, k0 = blockIdx.y * 32;
    const int t = threadIdx.x;
    const int r = t >> 3, c4 = (t & 7) * 4;
    float4 v = *(const float4*)&W[(size_t)(k0 + r) * N + n0 + c4];
    tile[r][c4 + 0] = v.x; tile[r][c4 + 1] = v.y;
    tile[r][c4 + 2] = v.z; tile[r][c4 + 3] = v.w;
    __syncthreads();
    ushort4 o;
    o.x = f2bf(tile[c4 + 0][r]);
    o.y = f2bf(tile[c4 + 1][r]);
    o.z = f2bf(tile[c4 + 2][r]);
    o.w = f2bf(tile[c4 + 3][r]);
    *(ushort4*)&WT[(size_t)(n0 + r) * K + k0 + c4] = o;
}

// ---------------- concat 3 bias vectors of 1024 ----------------
__global__ __launch_bounds__(256)
void concat3(const float* __restrict__ a, const float* __restrict__ b,
             const float* __restrict__ c, float* __restrict__ o) {
    const int i = blockIdx.x * 256 + threadIdx.x;
    o[i] = (i < 1024) ? a[i] : ((i < 2048) ? b[i - 1024] : c[i - 2048]);
}

// ---------------- bf16 MFMA GEMM, BK=64 (twin buffers) + XCD swizzle ------
// C[M,N] = A[M,K] @ Bt[N,K]^T + bias. gridDim.y (m-blocks) must be /8.
// relu / obf16 / qlim (cols<qlim scaled 0.125) / vn0 (cols>=vn0 -> Vt transposed)
template<int BN>
__global__ __launch_bounds__(256)
void gemm_bf16(const ushort* __restrict__ A, const ushort* __restrict__ Bt,
               const float* __restrict__ bias, void* __restrict__ C,
               ushort* __restrict__ Vt, int vn0,
               int M, int N, int K, int relu, int obf16, int qlim) {
    constexpr int JF = BN / 32;        // j-frags per wave
    __shared__ ushort Als0[128 * 32];  // k0..k0+32
    __shared__ ushort Als1[128 * 32];  // k0+32..k0+64
    __shared__ ushort Bls0[BN * 32];
    __shared__ ushort Bls1[BN * 32];

    // XCD-aware swizzle: blocks with linear id ≡ k (mod 8) share XCD k.
    // Give each XCD a compact contiguous m-range for L2 locality.
    const int L = blockIdx.x + gridDim.x * blockIdx.y;
    const int xcd = L & 7;
    const int idx = L >> 3;
    const int mpx = gridDim.y >> 3;    // m-blocks per XCD
    const int bm = (xcd * mpx + (idx % mpx)) * 128;
    const int bn = (idx / mpx) * BN;

    const int t = threadIdx.x;
    const int lane = t & 63;
    const int w = t >> 6;
    const int wm = (w >> 1) * 64;
    const int wn = (w & 1) * (BN / 2);
    const int fm = lane & 15;
    const int kg = lane >> 4;

    f32x4 acc[4][JF] = {};

    for (int k0 = 0; k0 < K; k0 += 64) {
        // stage A halves (each 128x32 = 512 chunks of 16B)
        #pragma unroll
        for (int j = 0; j < 2; ++j) {
            const int chunk = j * 256 + t;
            const int row = chunk >> 2, kc = chunk & 3;
            const ushort* ga0 = A + (size_t)(bm + row) * K + k0 + kc * 8;
            __builtin_amdgcn_global_load_lds(
                (const __attribute__((address_space(1))) void*)ga0,
                (__attribute__((address_space(3))) void*)(Als0 + chunk * 8), 16, 0, 0);
            const ushort* ga1 = ga0 + 32;
            __builtin_amdgcn_global_load_lds(
                (const __attribute__((address_space(1))) void*)ga1,
                (__attribute__((address_space(3))) void*)(Als1 + chunk * 8), 16, 0, 0);
        }
        // stage B halves
        #pragma unroll
        for (int j = 0; j < BN / 64; ++j) {
            const int chunk = j * 256 + t;
            const int row = chunk >> 2, kc = chunk & 3;
            const ushort* gb0 = Bt + (size_t)(bn + row) * K + k0 + kc * 8;
            __builtin_amdgcn_global_load_lds(
                (const __attribute__((address_space(1))) void*)gb0,
                (__attribute__((address_space(3))) void*)(Bls0 + chunk * 8), 16, 0, 0);
            const ushort* gb1 = gb0 + 32;
            __builtin_amdgcn_global_load_lds(
                (const __attribute__((address_space(1))) void*)gb1,
                (__attribute__((address_space(3))) void*)(Bls1 + chunk * 8), 16, 0, 0);
        }
        __syncthreads();

        short8 af[4][2], bfr[JF][2];
        #pragma unroll
        for (int i = 0; i < 4; ++i) {
            af[i][0] = *(const short8*)&Als0[(wm + i * 16 + fm) * 32 + kg * 8];
            af[i][1] = *(const short8*)&Als1[(wm + i * 16 + fm) * 32 + kg * 8];
        }
        #pragma unroll
        for (int j = 0; j < JF; ++j) {
            bfr[j][0] = *(const short8*)&Bls0[(wn + j * 16 + fm) * 32 + kg * 8];
            bfr[j][1] = *(const short8*)&Bls1[(wn + j * 16 + fm) * 32 + kg * 8];
        }
        #pragma unroll
        for (int i = 0; i < 4; ++i)
            #pragma unroll
            for (int j = 0; j < JF; ++j) {
                acc[i][j] = __builtin_amdgcn_mfma_f32_16x16x32_bf16(
                    af[i][0], bfr[j][0], acc[i][j], 0, 0, 0);
                acc[i][j] = __builtin_amdgcn_mfma_f32_16x16x32_bf16(
                    af[i][1], bfr[j][1], acc[i][j], 0, 0, 0);
            }
        __syncthreads();
    }

    const int orow0 = (lane >> 4) * 4;
    const int ocol = lane & 15;
    #pragma unroll
    for (int j = 0; j < JF; ++j) {
        const int n = bn + wn + j * 16 + ocol;
        const float bv = bias[n];
        const bool isV = (bn + wn + j * 16) >= vn0;   // frag-uniform
        #pragma unroll
        for (int i = 0; i < 4; ++i) {
            const int m0 = bm + wm + i * 16 + orow0;
            if (isV) {
                ushort4 o;
                float v0 = acc[i][j][0] + bv, v1 = acc[i][j][1] + bv;
                float v2 = acc[i][j][2] + bv, v3 = acc[i][j][3] + bv;
                o.x = f2bf(v0); o.y = f2bf(v1); o.z = f2bf(v2); o.w = f2bf(v3);
                *(ushort4*)&Vt[((size_t)((m0 >> 10) << 10) + (n - vn0)) * 1024 + (m0 & 1023)] = o;
            } else {
                #pragma unroll
                for (int r = 0; r < 4; ++r) {
                    const int m = m0 + r;
                    float v = acc[i][j][r] + bv;
                    if (relu) v = fmaxf(v, 0.0f);
                    if (n < qlim) v *= 0.125f;
                    if (obf16)
                        ((ushort*)C)[(size_t)m * N + n] = f2bf(v);
                    else
                        ((float*)C)[(size_t)m * N + n] = v;
                }
            }
        }
    }
}

// ---------------- MFMA flash attention, 128-q-tile + reg prefetch ----------
__global__ __launch_bounds__(256, 2)
void attn_mfma(const ushort* __restrict__ QKVb, const ushort* __restrict__ Vt,
               const ushort* __restrict__ biasb, const int* __restrict__ mask,
               ushort* __restrict__ ctx) {
    const int q0 = blockIdx.x * 128;
    const int h = blockIdx.y;
    const int b = blockIdx.z;
    const int t = threadIdx.x;
    const int lane = t & 63;
    const int w = t >> 6;
    const int g = lane >> 4;     // quad
    const int c = lane & 15;

    __shared__ ushort Qs[128 * 72];
    __shared__ ushort Ks[64 * 72];
    __shared__ ushort Vs[64 * 72];
    __shared__ ushort Bs[128 * 72];    // bias tile [q][k], bf16
    __shared__ ushort Ps[4][32 * 72];
    __shared__ int maskS[LL];

    // ---- stage Q tile (128x64 bf16) + mask row ----
    #pragma unroll
    for (int i = 0; i < 4; ++i) {
        const int chunk = i * 256 + t;
        const int row = chunk >> 3, c8 = (chunk & 7) * 8;
        *(short8*)&Qs[row * 72 + c8] =
            *(const short8*)(QKVb + ((size_t)(b * LL + q0 + row)) * LDQ + h * DHH + c8);
    }
    ((int4*)maskS)[t] = ((const int4*)(mask + b * LL))[t];

    // ---- prefetch tile kt=0 into registers ----
    short8 pk[2], pv[2], pb[4];
    #pragma unroll
    for (int i = 0; i < 2; ++i) {
        const int chunk = i * 256 + t;
        const int row = chunk >> 3, c8 = (chunk & 7) * 8;
        pk[i] = *(const short8*)(QKVb + ((size_t)(b * LL + row)) * LDQ + 1024 + h * DHH + c8);
        pv[i] = *(const short8*)(Vt + ((size_t)((b * HH + h) * DHH + row)) * LL + c8);
    }
    #pragma unroll
    for (int i = 0; i < 4; ++i) {
        const int chunk = i * 256 + t;
        const int row = chunk >> 3, c8 = (chunk & 7) * 8;
        pb[i] = *(const short8*)(biasb + ((size_t)(b * LL + q0 + row)) * LL + c8);
    }
    __syncthreads();

    // preload Q A-frags (loop-invariant)
    short8 aq[2][2];
    #pragma unroll
    for (int p = 0; p < 2; ++p) {
        aq[p][0] = *(const short8*)&Qs[(w * 32 + p * 16 + c) * 72 + g * 8];
        aq[p][1] = *(const short8*)&Qs[(w * 32 + p * 16 + c) * 72 + g * 8 + 32];
    }

    float m_pr[2][4], l_run[2][4];
    f32x4 acc_o[2][4] = {};
    #pragma unroll
    for (int p = 0; p < 2; ++p)
        #pragma unroll
        for (int r = 0; r < 4; ++r) { m_pr[p][r] = -3.4e38f; l_run[p][r] = 0.0f; }

    for (int kt = 0; kt < 16; ++kt) {
        // ---- write prefetched K/V/bias tile to LDS ----
        #pragma unroll
        for (int i = 0; i < 2; ++i) {
            const int chunk = i * 256 + t;
            const int row = chunk >> 3, c8 = (chunk & 7) * 8;
            *(short8*)&Ks[row * 72 + c8] = pk[i];
            *(short8*)&Vs[row * 72 + c8] = pv[i];
        }
        #pragma unroll
        for (int i = 0; i < 4; ++i) {
            const int chunk = i * 256 + t;
            const int row = chunk >> 3, c8 = (chunk & 7) * 8;
            *(short8*)&Bs[row * 72 + c8] = pb[i];
        }
        __syncthreads();

        // ---- prefetch tile kt+1 ----
        if (kt < 15) {
            const int k0n = (kt + 1) * 64;
            #pragma unroll
            for (int i = 0; i < 2; ++i) {
                const int chunk = i * 256 + t;
                const int row = chunk >> 3, c8 = (chunk & 7) * 8;
                pk[i] = *(const short8*)(QKVb + ((size_t)(b * LL + k0n + row)) * LDQ + 1024 + h * DHH + c8);
                pv[i] = *(const short8*)(Vt + ((size_t)((b * HH + h) * DHH + row)) * LL + k0n + c8);
            }
            #pragma unroll
            for (int i = 0; i < 4; ++i) {
                const int chunk = i * 256 + t;
                const int row = chunk >> 3, c8 = (chunk & 7) * 8;
                pb[i] = *(const short8*)(biasb + ((size_t)(b * LL + q0 + row)) * LL + k0n + c8);
            }
        }
        const int k0 = kt * 64;

        // ---- S = Q.K^T ----
        f32x4 accs[2][4] = {};
        #pragma unroll
        for (int j = 0; j < 4; ++j) {
            short8 bk0 = *(const short8*)&Ks[(j * 16 + c) * 72 + g * 8];
            short8 bk1 = *(const short8*)&Ks[(j * 16 + c) * 72 + g * 8 + 32];
            #pragma unroll
            for (int p = 0; p < 2; ++p) {
                accs[p][j] = __builtin_amdgcn_mfma_f32_16x16x32_bf16(aq[p][0], bk0, accs[p][j], 0, 0, 0);
                accs[p][j] = __builtin_amdgcn_mfma_f32_16x16x32_bf16(aq[p][1], bk1, accs[p][j], 0, 0, 0);
            }
        }

        int mk[4];
        #pragma unroll
        for (int j = 0; j < 4; ++j) mk[j] = maskS[k0 + j * 16 + c];

        #pragma unroll
        for (int p = 0; p < 2; ++p) {
            float sc[4][4];
            #pragma unroll
            for (int j = 0; j < 4; ++j)
                #pragma unroll
                for (int r = 0; r < 4; ++r) {
                    const float bw = bf2f(Bs[(w * 32 + p * 16 + 4 * g + r) * 72 + j * 16 + c]);
                    float v = accs[p][j][r] * bw;
                    sc[j][r] = (mk[j] == 0) ? -10000.0f : v;
                }

            float mt[4];
            #pragma unroll
            for (int r = 0; r < 4; ++r)
                mt[r] = fmaxf(fmaxf(sc[0][r], sc[1][r]), fmaxf(sc[2][r], sc[3][r]));
            #pragma unroll
            for (int d = 1; d < 16; d <<= 1)
                #pragma unroll
                for (int r = 0; r < 4; ++r)
                    mt[r] = fmaxf(mt[r], __shfl_xor(mt[r], d));

            float al[4], lt[4];
            #pragma unroll
            for (int r = 0; r < 4; ++r) {
                float mn = fmaxf(m_pr[p][r], mt[r]);
                al[r] = __expf(m_pr[p][r] - mn);
                m_pr[p][r] = mn;
                lt[r] = 0.0f;
            }

            #pragma unroll
            for (int j = 0; j < 4; ++j)
                #pragma unroll
                for (int r = 0; r < 4; ++r) {
                    float pe = __expf(sc[j][r] - m_pr[p][r]);
                    lt[r] += pe;
                    Ps[w][(p * 16 + 4 * g + r) * 72 + j * 16 + c] = f2bf(pe);
                }
            #pragma unroll
            for (int d = 1; d < 16; d <<= 1)
                #pragma unroll
                for (int r = 0; r < 4; ++r)
                    lt[r] += __shfl_xor(lt[r], d);
            #pragma unroll
            for (int r = 0; r < 4; ++r)
                l_run[p][r] = l_run[p][r] * al[r] + lt[r];

            #pragma unroll
            for (int j = 0; j < 4; ++j)
                #pragma unroll
                for (int r = 0; r < 4; ++r)
                    acc_o[p][j][r] *= al[r];
        }

        // ---- O += P.V ----
        #pragma unroll
        for (int ks = 0; ks < 2; ++ks) {
            short8 ap[2];
            #pragma unroll
            for (int p = 0; p < 2; ++p)
                ap[p] = *(const short8*)&Ps[w][(p * 16 + c) * 72 + ks * 32 + g * 8];
            #pragma unroll
            for (int j = 0; j < 4; ++j) {
                short8 bv8 = *(const short8*)&Vs[(j * 16 + c) * 72 + ks * 32 + g * 8];
                #pragma unroll
                for (int p = 0; p < 2; ++p)
                    acc_o[p][j] = __builtin_amdgcn_mfma_f32_16x16x32_bf16(ap[p], bv8, acc_o[p][j], 0, 0, 0);
            }
        }
        __syncthreads();
    }

    // ---- epilogue ----
    #pragma unroll
    for (int p = 0; p < 2; ++p)
        #pragma unroll
        for (int r = 0; r < 4; ++r) {
            const float inv = 1.0f / l_run[p][r];
            #pragma unroll
            for (int j = 0; j < 4; ++j)
                ctx[((size_t)(b * LL + q0 + w * 32 + p * 16 + 4 * g + r)) * DD + h * DHH + j * 16 + c] =
                    f2bf(acc_o[p][j][r] * inv);
        }
}

// ---------------- residual add + LayerNorm (optional bf16 copy) ------------
__global__ __launch_bounds__(256)
void add_ln_kernel(const float* __restrict__ a, const float* __restrict__ bres,
                   const float* __restrict__ gamma, const float* __restrict__ beta,
                   float* __restrict__ out, ushort* __restrict__ outb) {
    const int row = blockIdx.x;
    const int tid = threadIdx.x;
    __shared__ float red[256];

    const size_t base = (size_t)row * DD;
    float v[4];
    float sum = 0.0f;
    #pragma unroll
    for (int i = 0; i < 4; ++i) {
        const int col = tid + i * 256;
        v[i] = a[base + col] + bres[base + col];
        sum += v[i];
    }
    const float mean = block_reduce_sum(sum, red, tid) * (1.0f / 1024.0f);
    float vs = 0.0f;
    #pragma unroll
    for (int i = 0; i < 4; ++i) {
        const float dlt = v[i] - mean;
        vs += dlt * dlt;
    }
    const float var = block_reduce_sum(vs, red, tid) * (1.0f / 1024.0f);
    const float rstd = rsqrtf(var + 1e-12f);
    #pragma unroll
    for (int i = 0; i < 4; ++i) {
        const int col = tid + i * 256;
        const float o = gamma[col] * (v[i] - mean) * rstd + beta[col];
        out[base + col] = o;
        if (outb) outb[base + col] = f2bf(o);
    }
}

extern "C" void kernel_launch(void* const* d_in, const int* in_sizes, int n_in,
                              void* d_out, int out_size, void* d_ws, size_t ws_size,
                              hipStream_t stream) {
    const float* x         = (const float*)d_in[0];
    const float* attn_bias = (const float*)d_in[1];
    const int*   src_mask  = (const int*)  d_in[2];
    const float* wq = (const float*)d_in[3];
    const float* bq = (const float*)d_in[4];
    const float* wk = (const float*)d_in[5];
    const float* bk = (const float*)d_in[6];
    const float* wv = (const float*)d_in[7];
    const float* bv = (const float*)d_in[8];
    const float* wo = (const float*)d_in[9];
    const float* bo = (const float*)d_in[10];
    const float* gamma1 = (const float*)d_in[11];
    const float* beta1  = (const float*)d_in[12];
    const float* w1 = (const float*)d_in[13];
    const float* b1 = (const float*)d_in[14];
    const float* w2 = (const float*)d_in[15];
    const float* b2 = (const float*)d_in[16];
    const float* gamma2 = (const float*)d_in[17];
    const float* beta2  = (const float*)d_in[18];
    float* out = (float*)d_out;

    // workspace arena (96 MB, time-multiplexed)
    const size_t MB = 1024 * 1024;
    char* W = (char*)d_ws;
    ushort* xb    = (ushort*)(W + 0);        // 8 MB; dead after QKV gemm
    ushort* ctxb  = (ushort*)(W + 0);        // 8 MB (attn output)
    ushort* QKVb  = (ushort*)(W + 8 * MB);   // 24 MB bf16 [4096][3072]; dead after attn
    ushort* F1b   = (ushort*)(W + 8 * MB);   // 32 MB bf16 (FFN1 out)
    ushort* Vt    = (ushort*)(W + 40 * MB);  // 8 MB bf16 [b*16+h][64 d][1024 k]
    ushort* W1T   = (ushort*)(W + 40 * MB);  // 8 MB (transpose after attn)
    ushort* WQKVT = (ushort*)(W + 48 * MB);  // 6 MB; dead after QKV gemm
    ushort* WOT   = (ushort*)(W + 48 * MB);  // 2 MB
    ushort* Hbb   = (ushort*)(W + 54 * MB);  // 8 MB bf16 h; dead after FFN1
    ushort* W2T   = (ushort*)(W + 54 * MB);  // 8 MB (transpose after FFN1)
    float*  bqkv  = (float*) (W + 62 * MB);  // 12 KB
    ushort* biasb = (ushort*)(W + 64 * MB);  // 8.4 MB bf16 bias; dead before WO gemm
    float*  Ao    = (float*) (W + 64 * MB);  // 16 MB fp32; dead after LN1 (overwrites biasb)
    float*  F2    = (float*) (W + 64 * MB);  // 16 MB fp32
    float*  Hb    = (float*) (W + 80 * MB);  // 16 MB fp32 (live to end)

    dim3 blk(256);

    // 1. cast x -> bf16; cast attn_bias -> bf16
    cast_bf16<<<dim3(4096), blk, 0, stream>>>(x, xb);
    cast_bf16<<<dim3(4096), blk, 0, stream>>>(attn_bias, biasb);
    // 2. QKV weight transposes + bias concat
    transpose_cast<<<dim3(32, 32), blk, 0, stream>>>(wq, WQKVT, DD, DD);
    transpose_cast<<<dim3(32, 32), blk, 0, stream>>>(wk, WQKVT + 1024 * 1024, DD, DD);
    transpose_cast<<<dim3(32, 32), blk, 0, stream>>>(wv, WQKVT + 2048 * 1024, DD, DD);
    concat3<<<dim3(12), blk, 0, stream>>>(bq, bk, bv, bqkv);
    // 3. fused QKV projection (bf16 out; Q scaled 0.125; V -> Vt transposed)
    gemm_bf16<128><<<dim3(24, 32), blk, 0, stream>>>(xb, WQKVT, bqkv, QKVb,
                                                     Vt, 2048, MM, LDQ, DD, 0, 1, 1024);
    // 4. MFMA flash attention -> ctx bf16 (128-row q-tiles)
    attn_mfma<<<dim3(8, HH, BB), blk, 0, stream>>>(QKVb, Vt, biasb, src_mask, ctxb);
    // 5. WO transpose + output projection (fp32 out)
    transpose_cast<<<dim3(32, 32), blk, 0, stream>>>(wo, WOT, DD, DD);
    gemm_bf16<64><<<dim3(16, 32), blk, 0, stream>>>(ctxb, WOT, bo, Ao,
                                                    Vt, 1 << 30, MM, DD, DD, 0, 0, 0);
    // 6. h = LN(x + attn_out), fp32 + bf16
    add_ln_kernel<<<dim3(MM), blk, 0, stream>>>(Ao, x, gamma1, beta1, Hb, Hbb);
    // 7. FFN1 (relu, bf16 out)
    transpose_cast<<<dim3(128, 32), blk, 0, stream>>>(w1, W1T, DD, FFF);
    gemm_bf16<128><<<dim3(32, 32), blk, 0, stream>>>(Hbb, W1T, b1, F1b,
                                                     Vt, 1 << 30, MM, FFF, DD, 1, 1, 0);
    // 8. FFN2 (fp32 out)
    transpose_cast<<<dim3(32, 128), blk, 0, stream>>>(w2, W2T, FFF, DD);
    gemm_bf16<64><<<dim3(16, 32), blk, 0, stream>>>(F1b, W2T, b2, F2,
                                                    Vt, 1 << 30, MM, DD, FFF, 0, 0, 0);
    // 9. out = LN(h + ffn)
    add_ln_kernel<<<dim3(MM), blk, 0, stream>>>(F2, Hb, gamma2, beta2, out, nullptr);
}

// Round 9
// 400.635 us; speedup vs baseline: 12.5177x; 1.0479x over previous
//
#include <hip/hip_runtime.h>
#include <hip/hip_bf16.h>
#include <math.h>

// Problem constants
#define BB 4
#define LL 1024
#define DD 1024
#define HH 16
#define DHH 64
#define FFF 4096
#define MM (BB*LL)     // 4096 rows
#define LDQ 3072       // fused QKV row stride

typedef __attribute__((ext_vector_type(8))) short short8;
typedef __attribute__((ext_vector_type(4))) float f32x4;

__device__ __forceinline__ ushort f2bf(float f) {
    __hip_bfloat16 h = __float2bfloat16(f);
    return *(ushort*)&h;
}
__device__ __forceinline__ float bf2f(ushort u) {
    __hip_bfloat16 h = *(__hip_bfloat16*)&u;
    return __bfloat162float(h);
}
__device__ __forceinline__ float fexp2(float x) {
#if __has_builtin(__builtin_amdgcn_exp2f)
    return __builtin_amdgcn_exp2f(x);
#else
    return exp2f(x);
#endif
}

// ---------------- block reduction helper ----------------
__device__ __forceinline__ float block_reduce_sum(float v, float* red, int tid) {
    red[tid] = v;
    __syncthreads();
    for (int off = 128; off > 0; off >>= 1) {
        if (tid < off) red[tid] += red[tid + off];
        __syncthreads();
    }
    float r = red[0];
    __syncthreads();
    return r;
}

// ---------------- elementwise cast fp32 -> bf16 ----------------
__global__ __launch_bounds__(256)
void cast_bf16(const float* __restrict__ in, ushort* __restrict__ out) {
    const int i = blockIdx.x * 256 + threadIdx.x;
    float4 v = ((const float4*)in)[i];
    ushort4 o;
    o.x = f2bf(v.x); o.y = f2bf(v.y); o.z = f2bf(v.z); o.w = f2bf(v.w);
    ((ushort4*)out)[i] = o;
}

// ---------------- bias pre-swizzle: fp32 [row][k] -> bf16 [row][kt][c*4+j] --
// k = kt*64 + j*16 + c; value scaled by log2(e) so softmax runs in exp2 domain.
__global__ __launch_bounds__(256)
void swizzle_bias(const float* __restrict__ bias, ushort* __restrict__ B) {
    __shared__ float rowbuf[1024];
    const int row = blockIdx.x;
    const int t = threadIdx.x;
    *(float4*)&rowbuf[t * 4] = *(const float4*)&bias[(size_t)row * 1024 + t * 4];
    __syncthreads();
    const int kt = t >> 4, c = t & 15;
    const float s = 1.4426950408889634f;
    ushort4 o;
    o.x = f2bf(rowbuf[kt * 64 + 0 * 16 + c] * s);
    o.y = f2bf(rowbuf[kt * 64 + 1 * 16 + c] * s);
    o.z = f2bf(rowbuf[kt * 64 + 2 * 16 + c] * s);
    o.w = f2bf(rowbuf[kt * 64 + 3 * 16 + c] * s);
    *(ushort4*)&B[(size_t)row * 1024 + t * 4] = o;
}

// ---------------- tiled transpose + cast: W[K][N] fp32 -> WT[N][K] bf16 ----
__global__ __launch_bounds__(256)
void transpose_cast(const float* __restrict__ W, ushort* __restrict__ WT,
                    int K, int N) {
    __shared__ float tile[32][33];
    const int n0 = blockIdx.x * 32, k0 = blockIdx.y * 32;
    const int t = threadIdx.x;
    const int r = t >> 3, c4 = (t & 7) * 4;
    float4 v = *(const float4*)&W[(size_t)(k0 + r) * N + n0 + c4];
    tile[r][c4 + 0] = v.x; tile[r][c4 + 1] = v.y;
    tile[r][c4 + 2] = v.z; tile[r][c4 + 3] = v.w;
    __syncthreads();
    ushort4 o;
    o.x = f2bf(tile[c4 + 0][r]);
    o.y = f2bf(tile[c4 + 1][r]);
    o.z = f2bf(tile[c4 + 2][r]);
    o.w = f2bf(tile[c4 + 3][r]);
    *(ushort4*)&WT[(size_t)(n0 + r) * K + k0 + c4] = o;
}

// ---------------- concat 3 bias vectors of 1024 ----------------
__global__ __launch_bounds__(256)
void concat3(const float* __restrict__ a, const float* __restrict__ b,
             const float* __restrict__ c, float* __restrict__ o) {
    const int i = blockIdx.x * 256 + threadIdx.x;
    o[i] = (i < 1024) ? a[i] : ((i < 2048) ? b[i - 1024] : c[i - 2048]);
}

// ---------------- bf16 MFMA GEMM, BK=64 (twin buffers) + XCD swizzle ------
template<int BN>
__global__ __launch_bounds__(256)
void gemm_bf16(const ushort* __restrict__ A, const ushort* __restrict__ Bt,
               const float* __restrict__ bias, void* __restrict__ C,
               ushort* __restrict__ Vt, int vn0,
               int M, int N, int K, int relu, int obf16, int qlim) {
    constexpr int JF = BN / 32;        // j-frags per wave
    __shared__ ushort Als0[128 * 32];
    __shared__ ushort Als1[128 * 32];
    __shared__ ushort Bls0[BN * 32];
    __shared__ ushort Bls1[BN * 32];

    // XCD-aware swizzle: compact m-range per XCD for L2 locality.
    const int L = blockIdx.x + gridDim.x * blockIdx.y;
    const int xcd = L & 7;
    const int idx = L >> 3;
    const int mpx = gridDim.y >> 3;
    const int bm = (xcd * mpx + (idx % mpx)) * 128;
    const int bn = (idx / mpx) * BN;

    const int t = threadIdx.x;
    const int lane = t & 63;
    const int w = t >> 6;
    const int wm = (w >> 1) * 64;
    const int wn = (w & 1) * (BN / 2);
    const int fm = lane & 15;
    const int kg = lane >> 4;

    f32x4 acc[4][JF] = {};

    for (int k0 = 0; k0 < K; k0 += 64) {
        #pragma unroll
        for (int j = 0; j < 2; ++j) {
            const int chunk = j * 256 + t;
            const int row = chunk >> 2, kc = chunk & 3;
            const ushort* ga0 = A + (size_t)(bm + row) * K + k0 + kc * 8;
            __builtin_amdgcn_global_load_lds(
                (const __attribute__((address_space(1))) void*)ga0,
                (__attribute__((address_space(3))) void*)(Als0 + chunk * 8), 16, 0, 0);
            const ushort* ga1 = ga0 + 32;
            __builtin_amdgcn_global_load_lds(
                (const __attribute__((address_space(1))) void*)ga1,
                (__attribute__((address_space(3))) void*)(Als1 + chunk * 8), 16, 0, 0);
        }
        #pragma unroll
        for (int j = 0; j < BN / 64; ++j) {
            const int chunk = j * 256 + t;
            const int row = chunk >> 2, kc = chunk & 3;
            const ushort* gb0 = Bt + (size_t)(bn + row) * K + k0 + kc * 8;
            __builtin_amdgcn_global_load_lds(
                (const __attribute__((address_space(1))) void*)gb0,
                (__attribute__((address_space(3))) void*)(Bls0 + chunk * 8), 16, 0, 0);
            const ushort* gb1 = gb0 + 32;
            __builtin_amdgcn_global_load_lds(
                (const __attribute__((address_space(1))) void*)gb1,
                (__attribute__((address_space(3))) void*)(Bls1 + chunk * 8), 16, 0, 0);
        }
        __syncthreads();

        short8 af[4][2], bfr[JF][2];
        #pragma unroll
        for (int i = 0; i < 4; ++i) {
            af[i][0] = *(const short8*)&Als0[(wm + i * 16 + fm) * 32 + kg * 8];
            af[i][1] = *(const short8*)&Als1[(wm + i * 16 + fm) * 32 + kg * 8];
        }
        #pragma unroll
        for (int j = 0; j < JF; ++j) {
            bfr[j][0] = *(const short8*)&Bls0[(wn + j * 16 + fm) * 32 + kg * 8];
            bfr[j][1] = *(const short8*)&Bls1[(wn + j * 16 + fm) * 32 + kg * 8];
        }
        #pragma unroll
        for (int i = 0; i < 4; ++i)
            #pragma unroll
            for (int j = 0; j < JF; ++j) {
                acc[i][j] = __builtin_amdgcn_mfma_f32_16x16x32_bf16(
                    af[i][0], bfr[j][0], acc[i][j], 0, 0, 0);
                acc[i][j] = __builtin_amdgcn_mfma_f32_16x16x32_bf16(
                    af[i][1], bfr[j][1], acc[i][j], 0, 0, 0);
            }
        __syncthreads();
    }

    const int orow0 = (lane >> 4) * 4;
    const int ocol = lane & 15;
    #pragma unroll
    for (int j = 0; j < JF; ++j) {
        const int n = bn + wn + j * 16 + ocol;
        const float bv = bias[n];
        const bool isV = (bn + wn + j * 16) >= vn0;
        #pragma unroll
        for (int i = 0; i < 4; ++i) {
            const int m0 = bm + wm + i * 16 + orow0;
            if (isV) {
                ushort4 o;
                float v0 = acc[i][j][0] + bv, v1 = acc[i][j][1] + bv;
                float v2 = acc[i][j][2] + bv, v3 = acc[i][j][3] + bv;
                o.x = f2bf(v0); o.y = f2bf(v1); o.z = f2bf(v2); o.w = f2bf(v3);
                *(ushort4*)&Vt[((size_t)((m0 >> 10) << 10) + (n - vn0)) * 1024 + (m0 & 1023)] = o;
            } else {
                #pragma unroll
                for (int r = 0; r < 4; ++r) {
                    const int m = m0 + r;
                    float v = acc[i][j][r] + bv;
                    if (relu) v = fmaxf(v, 0.0f);
                    if (n < qlim) v *= 0.125f;
                    if (obf16)
                        ((ushort*)C)[(size_t)m * N + n] = f2bf(v);
                    else
                        ((float*)C)[(size_t)m * N + n] = v;
                }
            }
        }
    }
}

// ---------------- MFMA flash attention, lean softmax ----------------
// Block = (b, h, 64-q-tile); wave w owns q-rows w*16..w*16+15.
// Q pre-scaled 0.125 in QKV GEMM; bias pre-swizzled bf16 in C-layout order
// with log2(e) folded (exp2 domain); Ps unioned onto dead Q-staging LDS;
// per-lane l partials reduced once in epilogue; rescale skipped when max
// unchanged across the whole wave.
__global__ __launch_bounds__(256, 3)
void attn_mfma(const ushort* __restrict__ QKVb, const ushort* __restrict__ Vt,
               const ushort* __restrict__ biasw, const int* __restrict__ mask,
               ushort* __restrict__ ctx) {
    const int q0 = blockIdx.x * 64;
    const int h = blockIdx.y;
    const int b = blockIdx.z;
    const int t = threadIdx.x;
    const int lane = t & 63;
    const int w = t >> 6;
    const int g = lane >> 4;     // quad
    const int c = lane & 15;

    __shared__ ushort QP[64 * 72];   // Q staging, then per-wave P tiles
    __shared__ ushort Ks[64 * 72];
    __shared__ ushort Vs[64 * 72];
    __shared__ int maskS[LL];

    // ---- stage Q tile + mask row ----
    #pragma unroll
    for (int i = 0; i < 2; ++i) {
        const int chunk = i * 256 + t;
        const int row = chunk >> 3, c8 = (chunk & 7) * 8;
        *(short8*)&QP[row * 72 + c8] =
            *(const short8*)(QKVb + ((size_t)(b * LL + q0 + row)) * LDQ + h * DHH + c8);
    }
    ((int4*)maskS)[t] = ((const int4*)(mask + b * LL))[t];

    // ---- prefetch K/V tile 0 into registers ----
    short8 pk[2], pv[2];
    #pragma unroll
    for (int i = 0; i < 2; ++i) {
        const int chunk = i * 256 + t;
        const int row = chunk >> 3, c8 = (chunk & 7) * 8;
        pk[i] = *(const short8*)(QKVb + ((size_t)(b * LL + row)) * LDQ + 1024 + h * DHH + c8);
        pv[i] = *(const short8*)(Vt + ((size_t)((b * HH + h) * DHH + row)) * LL + c8);
    }
    __syncthreads();

    // Q A-frags (loop-invariant); value dependency keeps reads before P writes
    short8 aq0 = *(const short8*)&QP[(w * 16 + c) * 72 + g * 8];
    short8 aq1 = *(const short8*)&QP[(w * 16 + c) * 72 + g * 8 + 32];
    ushort* Pw = QP + w * (16 * 72);   // wave-private P tile (overlays own Q rows)

    float m_pr[4] = {-3.4e38f, -3.4e38f, -3.4e38f, -3.4e38f};
    float l_run[4] = {0.f, 0.f, 0.f, 0.f};   // per-lane partials
    f32x4 acc_o[4] = {};

    for (int kt = 0; kt < 16; ++kt) {
        // ---- write prefetched K/V to LDS ----
        #pragma unroll
        for (int i = 0; i < 2; ++i) {
            const int chunk = i * 256 + t;
            const int row = chunk >> 3, c8 = (chunk & 7) * 8;
            *(short8*)&Ks[row * 72 + c8] = pk[i];
            *(short8*)&Vs[row * 72 + c8] = pv[i];
        }
        __syncthreads();

        // ---- prefetch K/V for kt+1 ----
        if (kt < 15) {
            const int k0n = (kt + 1) * 64;
            #pragma unroll
            for (int i = 0; i < 2; ++i) {
                const int chunk = i * 256 + t;
                const int row = chunk >> 3, c8 = (chunk & 7) * 8;
                pk[i] = *(const short8*)(QKVb + ((size_t)(b * LL + k0n + row)) * LDQ + 1024 + h * DHH + c8);
                pv[i] = *(const short8*)(Vt + ((size_t)((b * HH + h) * DHH + row)) * LL + k0n + c8);
            }
        }

        // ---- bias (pre-swizzled, coalesced) + mask, issued early ----
        ushort4 pb[4];
        #pragma unroll
        for (int r = 0; r < 4; ++r) {
            const int q = q0 + w * 16 + 4 * g + r;
            pb[r] = *(const ushort4*)&biasw[((size_t)(b * LL + q) * 16 + kt) * 64 + c * 4];
        }
        int mk[4];
        #pragma unroll
        for (int j = 0; j < 4; ++j) mk[j] = maskS[kt * 64 + j * 16 + c];

        // ---- S = Q.K^T ----
        f32x4 accs[4] = {};
        #pragma unroll
        for (int j = 0; j < 4; ++j) {
            short8 bk0 = *(const short8*)&Ks[(j * 16 + c) * 72 + g * 8];
            short8 bk1 = *(const short8*)&Ks[(j * 16 + c) * 72 + g * 8 + 32];
            accs[j] = __builtin_amdgcn_mfma_f32_16x16x32_bf16(aq0, bk0, accs[j], 0, 0, 0);
            accs[j] = __builtin_amdgcn_mfma_f32_16x16x32_bf16(aq1, bk1, accs[j], 0, 0, 0);
        }

        // ---- bias*S, mask (exp2 domain) ----
        float sc[4][4];
        #pragma unroll
        for (int j = 0; j < 4; ++j)
            #pragma unroll
            for (int r = 0; r < 4; ++r) {
                const float bw = bf2f(((const ushort*)&pb[r])[j]);
                const float v = accs[j][r] * bw;
                sc[j][r] = (mk[j] == 0) ? -14427.0f : v;
            }

        // ---- row max (16-lane butterfly) ----
        float mt[4];
        #pragma unroll
        for (int r = 0; r < 4; ++r)
            mt[r] = fmaxf(fmaxf(sc[0][r], sc[1][r]), fmaxf(sc[2][r], sc[3][r]));
        #pragma unroll
        for (int d = 1; d < 16; d <<= 1)
            #pragma unroll
            for (int r = 0; r < 4; ++r)
                mt[r] = fmaxf(mt[r], __shfl_xor(mt[r], d));

        float al[4], lt[4];
        #pragma unroll
        for (int r = 0; r < 4; ++r) {
            const float mn = fmaxf(m_pr[r], mt[r]);
            al[r] = fexp2(m_pr[r] - mn);
            m_pr[r] = mn;
            lt[r] = 0.0f;
        }

        // ---- P = exp2(sc - m), write bf16 (A-layout rows), lane-local l ----
        #pragma unroll
        for (int j = 0; j < 4; ++j)
            #pragma unroll
            for (int r = 0; r < 4; ++r) {
                const float pe = fexp2(sc[j][r] - m_pr[r]);
                lt[r] += pe;
                Pw[(4 * g + r) * 72 + j * 16 + c] = f2bf(pe);
            }

        // ---- rescale only if some row's max changed ----
        const bool ones = (al[0] == 1.0f) & (al[1] == 1.0f) &
                          (al[2] == 1.0f) & (al[3] == 1.0f);
        if (!__all(ones)) {
            #pragma unroll
            for (int r = 0; r < 4; ++r) l_run[r] *= al[r];
            #pragma unroll
            for (int j = 0; j < 4; ++j)
                #pragma unroll
                for (int r = 0; r < 4; ++r)
                    acc_o[j][r] *= al[r];
        }
        #pragma unroll
        for (int r = 0; r < 4; ++r) l_run[r] += lt[r];

        // ---- O += P.V ----
        #pragma unroll
        for (int ks = 0; ks < 2; ++ks) {
            short8 ap = *(const short8*)&Pw[c * 72 + ks * 32 + g * 8];
            #pragma unroll
            for (int j = 0; j < 4; ++j) {
                short8 bv8 = *(const short8*)&Vs[(j * 16 + c) * 72 + ks * 32 + g * 8];
                acc_o[j] = __builtin_amdgcn_mfma_f32_16x16x32_bf16(ap, bv8, acc_o[j], 0, 0, 0);
            }
        }
        __syncthreads();
    }

    // ---- epilogue: reduce l once, normalize, store ----
    #pragma unroll
    for (int r = 0; r < 4; ++r) {
        float l = l_run[r];
        #pragma unroll
        for (int d = 1; d < 16; d <<= 1) l += __shfl_xor(l, d);
        const float inv = 1.0f / l;
        #pragma unroll
        for (int j = 0; j < 4; ++j)
            ctx[((size_t)(b * LL + q0 + w * 16 + 4 * g + r)) * DD + h * DHH + j * 16 + c] =
                f2bf(acc_o[j][r] * inv);
    }
}

// ---------------- residual add + LayerNorm (optional bf16 copy) ------------
__global__ __launch_bounds__(256)
void add_ln_kernel(const float* __restrict__ a, const float* __restrict__ bres,
                   const float* __restrict__ gamma, const float* __restrict__ beta,
                   float* __restrict__ out, ushort* __restrict__ outb) {
    const int row = blockIdx.x;
    const int tid = threadIdx.x;
    __shared__ float red[256];

    const size_t base = (size_t)row * DD;
    float v[4];
    float sum = 0.0f;
    #pragma unroll
    for (int i = 0; i < 4; ++i) {
        const int col = tid + i * 256;
        v[i] = a[base + col] + bres[base + col];
        sum += v[i];
    }
    const float mean = block_reduce_sum(sum, red, tid) * (1.0f / 1024.0f);
    float vs = 0.0f;
    #pragma unroll
    for (int i = 0; i < 4; ++i) {
        const float dlt = v[i] - mean;
        vs += dlt * dlt;
    }
    const float var = block_reduce_sum(vs, red, tid) * (1.0f / 1024.0f);
    const float rstd = rsqrtf(var + 1e-12f);
    #pragma unroll
    for (int i = 0; i < 4; ++i) {
        const int col = tid + i * 256;
        const float o = gamma[col] * (v[i] - mean) * rstd + beta[col];
        out[base + col] = o;
        if (outb) outb[base + col] = f2bf(o);
    }
}

extern "C" void kernel_launch(void* const* d_in, const int* in_sizes, int n_in,
                              void* d_out, int out_size, void* d_ws, size_t ws_size,
                              hipStream_t stream) {
    const float* x         = (const float*)d_in[0];
    const float* attn_bias = (const float*)d_in[1];
    const int*   src_mask  = (const int*)  d_in[2];
    const float* wq = (const float*)d_in[3];
    const float* bq = (const float*)d_in[4];
    const float* wk = (const float*)d_in[5];
    const float* bk = (const float*)d_in[6];
    const float* wv = (const float*)d_in[7];
    const float* bv = (const float*)d_in[8];
    const float* wo = (const float*)d_in[9];
    const float* bo = (const float*)d_in[10];
    const float* gamma1 = (const float*)d_in[11];
    const float* beta1  = (const float*)d_in[12];
    const float* w1 = (const float*)d_in[13];
    const float* b1 = (const float*)d_in[14];
    const float* w2 = (const float*)d_in[15];
    const float* b2 = (const float*)d_in[16];
    const float* gamma2 = (const float*)d_in[17];
    const float* beta2  = (const float*)d_in[18];
    float* out = (float*)d_out;

    // workspace arena (96 MB, time-multiplexed)
    const size_t MB = 1024 * 1024;
    char* W = (char*)d_ws;
    ushort* xb    = (ushort*)(W + 0);        // 8 MB; dead after QKV gemm
    ushort* ctxb  = (ushort*)(W + 0);        // 8 MB (attn output)
    ushort* QKVb  = (ushort*)(W + 8 * MB);   // 24 MB bf16 [4096][3072]; dead after attn
    ushort* F1b   = (ushort*)(W + 8 * MB);   // 32 MB bf16 (FFN1 out)
    ushort* Vt    = (ushort*)(W + 40 * MB);  // 8 MB bf16 [b*16+h][64 d][1024 k]
    ushort* W1T   = (ushort*)(W + 40 * MB);  // 8 MB (transpose after attn)
    ushort* WQKVT = (ushort*)(W + 48 * MB);  // 6 MB; dead after QKV gemm
    ushort* WOT   = (ushort*)(W + 48 * MB);  // 2 MB
    ushort* Hbb   = (ushort*)(W + 54 * MB);  // 8 MB bf16 h; dead after FFN1
    ushort* W2T   = (ushort*)(W + 54 * MB);  // 8 MB (transpose after FFN1)
    float*  bqkv  = (float*) (W + 62 * MB);  // 12 KB
    ushort* biasw = (ushort*)(W + 64 * MB);  // 8.4 MB swizzled bf16 bias; dead before WO gemm
    float*  Ao    = (float*) (W + 64 * MB);  // 16 MB fp32; dead after LN1
    float*  F2    = (float*) (W + 64 * MB);  // 16 MB fp32
    float*  Hb    = (float*) (W + 80 * MB);  // 16 MB fp32 (live to end)

    dim3 blk(256);

    // 1. cast x -> bf16; pre-swizzle attn_bias (bf16, C-layout, log2e folded)
    cast_bf16<<<dim3(4096), blk, 0, stream>>>(x, xb);
    swizzle_bias<<<dim3(4096), blk, 0, stream>>>(attn_bias, biasw);
    // 2. QKV weight transposes + bias concat
    transpose_cast<<<dim3(32, 32), blk, 0, stream>>>(wq, WQKVT, DD, DD);
    transpose_cast<<<dim3(32, 32), blk, 0, stream>>>(wk, WQKVT + 1024 * 1024, DD, DD);
    transpose_cast<<<dim3(32, 32), blk, 0, stream>>>(wv, WQKVT + 2048 * 1024, DD, DD);
    concat3<<<dim3(12), blk, 0, stream>>>(bq, bk, bv, bqkv);
    // 3. fused QKV projection (bf16 out; Q scaled 0.125; V -> Vt transposed)
    gemm_bf16<128><<<dim3(24, 32), blk, 0, stream>>>(xb, WQKVT, bqkv, QKVb,
                                                     Vt, 2048, MM, LDQ, DD, 0, 1, 1024);
    // 4. MFMA flash attention -> ctx bf16 (64-row q-tiles, 1024 blocks)
    attn_mfma<<<dim3(16, HH, BB), blk, 0, stream>>>(QKVb, Vt, biasw, src_mask, ctxb);
    // 5. WO transpose + output projection (fp32 out)
    transpose_cast<<<dim3(32, 32), blk, 0, stream>>>(wo, WOT, DD, DD);
    gemm_bf16<64><<<dim3(16, 32), blk, 0, stream>>>(ctxb, WOT, bo, Ao,
                                                    Vt, 1 << 30, MM, DD, DD, 0, 0, 0);
    // 6. h = LN(x + attn_out), fp32 + bf16
    add_ln_kernel<<<dim3(MM), blk, 0, stream>>>(Ao, x, gamma1, beta1, Hb, Hbb);
    // 7. FFN1 (relu, bf16 out)
    transpose_cast<<<dim3(128, 32), blk, 0, stream>>>(w1, W1T, DD, FFF);
    gemm_bf16<128><<<dim3(32, 32), blk, 0, stream>>>(Hbb, W1T, b1, F1b,
                                                     Vt, 1 << 30, MM, FFF, DD, 1, 1, 0);
    // 8. FFN2 (fp32 out)
    transpose_cast<<<dim3(32, 128), blk, 0, stream>>>(w2, W2T, FFF, DD);
    gemm_bf16<64><<<dim3(16, 32), blk, 0, stream>>>(F1b, W2T, b2, F2,
                                                    Vt, 1 << 30, MM, DD, FFF, 0, 0, 0);
    // 9. out = LN(h + ffn)
    add_ln_kernel<<<dim3(MM), blk, 0, stream>>>(F2, Hb, gamma2, beta2, out, nullptr);
}

// Round 10
// 397.522 us; speedup vs baseline: 12.6157x; 1.0078x over previous
//
#include <hip/hip_runtime.h>
#include <hip/hip_bf16.h>
#include <math.h>

// Problem constants
#define BB 4
#define LL 1024
#define DD 1024
#define HH 16
#define DHH 64
#define FFF 4096
#define MM (BB*LL)     // 4096 rows
#define LDQ 3072       // fused QKV row stride

typedef __attribute__((ext_vector_type(8))) short short8;
typedef __attribute__((ext_vector_type(4))) float f32x4;

__device__ __forceinline__ ushort f2bf(float f) {
    __hip_bfloat16 h = __float2bfloat16(f);
    return *(ushort*)&h;
}
__device__ __forceinline__ float bf2f(ushort u) {
    __hip_bfloat16 h = *(__hip_bfloat16*)&u;
    return __bfloat162float(h);
}
__device__ __forceinline__ float fexp2(float x) {
#if __has_builtin(__builtin_amdgcn_exp2f)
    return __builtin_amdgcn_exp2f(x);
#else
    return exp2f(x);
#endif
}

// ---------------- block reduction helper ----------------
__device__ __forceinline__ float block_reduce_sum(float v, float* red, int tid) {
    red[tid] = v;
    __syncthreads();
    for (int off = 128; off > 0; off >>= 1) {
        if (tid < off) red[tid] += red[tid + off];
        __syncthreads();
    }
    float r = red[0];
    __syncthreads();
    return r;
}

// ---------------- elementwise cast fp32 -> bf16 ----------------
__global__ __launch_bounds__(256)
void cast_bf16(const float* __restrict__ in, ushort* __restrict__ out) {
    const int i = blockIdx.x * 256 + threadIdx.x;
    float4 v = ((const float4*)in)[i];
    ushort4 o;
    o.x = f2bf(v.x); o.y = f2bf(v.y); o.z = f2bf(v.z); o.w = f2bf(v.w);
    ((ushort4*)out)[i] = o;
}

// ---------------- bias pre-swizzle: fp32 [row][k] -> bf16 [row][kt][c*4+j] --
__global__ __launch_bounds__(256)
void swizzle_bias(const float* __restrict__ bias, ushort* __restrict__ B) {
    __shared__ float rowbuf[1024];
    const int row = blockIdx.x;
    const int t = threadIdx.x;
    *(float4*)&rowbuf[t * 4] = *(const float4*)&bias[(size_t)row * 1024 + t * 4];
    __syncthreads();
    const int kt = t >> 4, c = t & 15;
    const float s = 1.4426950408889634f;
    ushort4 o;
    o.x = f2bf(rowbuf[kt * 64 + 0 * 16 + c] * s);
    o.y = f2bf(rowbuf[kt * 64 + 1 * 16 + c] * s);
    o.z = f2bf(rowbuf[kt * 64 + 2 * 16 + c] * s);
    o.w = f2bf(rowbuf[kt * 64 + 3 * 16 + c] * s);
    *(ushort4*)&B[(size_t)row * 1024 + t * 4] = o;
}

// ---------------- tiled transpose + cast: W[K][N] fp32 -> WT[N][K] bf16 ----
__global__ __launch_bounds__(256)
void transpose_cast(const float* __restrict__ W, ushort* __restrict__ WT,
                    int K, int N) {
    __shared__ float tile[32][33];
    const int n0 = blockIdx.x * 32, k0 = blockIdx.y * 32;
    const int t = threadIdx.x;
    const int r = t >> 3, c4 = (t & 7) * 4;
    float4 v = *(const float4*)&W[(size_t)(k0 + r) * N + n0 + c4];
    tile[r][c4 + 0] = v.x; tile[r][c4 + 1] = v.y;
    tile[r][c4 + 2] = v.z; tile[r][c4 + 3] = v.w;
    __syncthreads();
    ushort4 o;
    o.x = f2bf(tile[c4 + 0][r]);
    o.y = f2bf(tile[c4 + 1][r]);
    o.z = f2bf(tile[c4 + 2][r]);
    o.w = f2bf(tile[c4 + 3][r]);
    *(ushort4*)&WT[(size_t)(n0 + r) * K + k0 + c4] = o;
}

// ---------------- concat 3 bias vectors of 1024 ----------------
__global__ __launch_bounds__(256)
void concat3(const float* __restrict__ a, const float* __restrict__ b,
             const float* __restrict__ c, float* __restrict__ o) {
    const int i = blockIdx.x * 256 + threadIdx.x;
    o[i] = (i < 1024) ? a[i] : ((i < 2048) ? b[i - 1024] : c[i - 2048]);
}

// ---------------- bf16 MFMA GEMM, BK=64 (twin buffers) + XCD swizzle ------
// Full-K version (QKV, FFN1). Same options as before.
template<int BN>
__global__ __launch_bounds__(256)
void gemm_bf16(const ushort* __restrict__ A, const ushort* __restrict__ Bt,
               const float* __restrict__ bias, void* __restrict__ C,
               ushort* __restrict__ Vt, int vn0,
               int M, int N, int K, int relu, int obf16, int qlim) {
    constexpr int JF = BN / 32;
    __shared__ ushort Als0[128 * 32];
    __shared__ ushort Als1[128 * 32];
    __shared__ ushort Bls0[BN * 32];
    __shared__ ushort Bls1[BN * 32];

    const int L = blockIdx.x + gridDim.x * blockIdx.y;
    const int xcd = L & 7;
    const int idx = L >> 3;
    const int mpx = gridDim.y >> 3;
    const int bm = (xcd * mpx + (idx % mpx)) * 128;
    const int bn = (idx / mpx) * BN;

    const int t = threadIdx.x;
    const int lane = t & 63;
    const int w = t >> 6;
    const int wm = (w >> 1) * 64;
    const int wn = (w & 1) * (BN / 2);
    const int fm = lane & 15;
    const int kg = lane >> 4;

    f32x4 acc[4][JF] = {};

    for (int k0 = 0; k0 < K; k0 += 64) {
        #pragma unroll
        for (int j = 0; j < 2; ++j) {
            const int chunk = j * 256 + t;
            const int row = chunk >> 2, kc = chunk & 3;
            const ushort* ga0 = A + (size_t)(bm + row) * K + k0 + kc * 8;
            __builtin_amdgcn_global_load_lds(
                (const __attribute__((address_space(1))) void*)ga0,
                (__attribute__((address_space(3))) void*)(Als0 + chunk * 8), 16, 0, 0);
            const ushort* ga1 = ga0 + 32;
            __builtin_amdgcn_global_load_lds(
                (const __attribute__((address_space(1))) void*)ga1,
                (__attribute__((address_space(3))) void*)(Als1 + chunk * 8), 16, 0, 0);
        }
        #pragma unroll
        for (int j = 0; j < BN / 64; ++j) {
            const int chunk = j * 256 + t;
            const int row = chunk >> 2, kc = chunk & 3;
            const ushort* gb0 = Bt + (size_t)(bn + row) * K + k0 + kc * 8;
            __builtin_amdgcn_global_load_lds(
                (const __attribute__((address_space(1))) void*)gb0,
                (__attribute__((address_space(3))) void*)(Bls0 + chunk * 8), 16, 0, 0);
            const ushort* gb1 = gb0 + 32;
            __builtin_amdgcn_global_load_lds(
                (const __attribute__((address_space(1))) void*)gb1,
                (__attribute__((address_space(3))) void*)(Bls1 + chunk * 8), 16, 0, 0);
        }
        __syncthreads();

        short8 af[4][2], bfr[JF][2];
        #pragma unroll
        for (int i = 0; i < 4; ++i) {
            af[i][0] = *(const short8*)&Als0[(wm + i * 16 + fm) * 32 + kg * 8];
            af[i][1] = *(const short8*)&Als1[(wm + i * 16 + fm) * 32 + kg * 8];
        }
        #pragma unroll
        for (int j = 0; j < JF; ++j) {
            bfr[j][0] = *(const short8*)&Bls0[(wn + j * 16 + fm) * 32 + kg * 8];
            bfr[j][1] = *(const short8*)&Bls1[(wn + j * 16 + fm) * 32 + kg * 8];
        }
        #pragma unroll
        for (int i = 0; i < 4; ++i)
            #pragma unroll
            for (int j = 0; j < JF; ++j) {
                acc[i][j] = __builtin_amdgcn_mfma_f32_16x16x32_bf16(
                    af[i][0], bfr[j][0], acc[i][j], 0, 0, 0);
                acc[i][j] = __builtin_amdgcn_mfma_f32_16x16x32_bf16(
                    af[i][1], bfr[j][1], acc[i][j], 0, 0, 0);
            }
        __syncthreads();
    }

    const int orow0 = (lane >> 4) * 4;
    const int ocol = lane & 15;
    #pragma unroll
    for (int j = 0; j < JF; ++j) {
        const int n = bn + wn + j * 16 + ocol;
        const float bv = bias[n];
        const bool isV = (bn + wn + j * 16) >= vn0;
        #pragma unroll
        for (int i = 0; i < 4; ++i) {
            const int m0 = bm + wm + i * 16 + orow0;
            if (isV) {
                ushort4 o;
                float v0 = acc[i][j][0] + bv, v1 = acc[i][j][1] + bv;
                float v2 = acc[i][j][2] + bv, v3 = acc[i][j][3] + bv;
                o.x = f2bf(v0); o.y = f2bf(v1); o.z = f2bf(v2); o.w = f2bf(v3);
                *(ushort4*)&Vt[((size_t)((m0 >> 10) << 10) + (n - vn0)) * 1024 + (m0 & 1023)] = o;
            } else {
                #pragma unroll
                for (int r = 0; r < 4; ++r) {
                    const int m = m0 + r;
                    float v = acc[i][j][r] + bv;
                    if (relu) v = fmaxf(v, 0.0f);
                    if (n < qlim) v *= 0.125f;
                    if (obf16)
                        ((ushort*)C)[(size_t)m * N + n] = f2bf(v);
                    else
                        ((float*)C)[(size_t)m * N + n] = v;
                }
            }
        }
    }
}

// ---------------- split-K bf16 MFMA GEMM (BN=64), fp32 partials -----------
// blockIdx.z = K-half. P[z][m][n] = sum over K-half. No bias (added in LN).
template<int BN>
__global__ __launch_bounds__(256)
void gemm_bf16_sk(const ushort* __restrict__ A, const ushort* __restrict__ Bt,
                  float* __restrict__ P, int M, int N, int K) {
    constexpr int JF = BN / 32;
    __shared__ ushort Als0[128 * 32];
    __shared__ ushort Als1[128 * 32];
    __shared__ ushort Bls0[BN * 32];
    __shared__ ushort Bls1[BN * 32];

    const int L = blockIdx.x + gridDim.x * blockIdx.y;
    const int xcd = L & 7;
    const int idx = L >> 3;
    const int mpx = gridDim.y >> 3;
    const int bm = (xcd * mpx + (idx % mpx)) * 128;
    const int bn = (idx / mpx) * BN;
    const int kbeg = blockIdx.z * (K >> 1);
    const int kend = kbeg + (K >> 1);

    const int t = threadIdx.x;
    const int lane = t & 63;
    const int w = t >> 6;
    const int wm = (w >> 1) * 64;
    const int wn = (w & 1) * (BN / 2);
    const int fm = lane & 15;
    const int kg = lane >> 4;

    f32x4 acc[4][JF] = {};

    for (int k0 = kbeg; k0 < kend; k0 += 64) {
        #pragma unroll
        for (int j = 0; j < 2; ++j) {
            const int chunk = j * 256 + t;
            const int row = chunk >> 2, kc = chunk & 3;
            const ushort* ga0 = A + (size_t)(bm + row) * K + k0 + kc * 8;
            __builtin_amdgcn_global_load_lds(
                (const __attribute__((address_space(1))) void*)ga0,
                (__attribute__((address_space(3))) void*)(Als0 + chunk * 8), 16, 0, 0);
            const ushort* ga1 = ga0 + 32;
            __builtin_amdgcn_global_load_lds(
                (const __attribute__((address_space(1))) void*)ga1,
                (__attribute__((address_space(3))) void*)(Als1 + chunk * 8), 16, 0, 0);
        }
        #pragma unroll
        for (int j = 0; j < BN / 64; ++j) {
            const int chunk = j * 256 + t;
            const int row = chunk >> 2, kc = chunk & 3;
            const ushort* gb0 = Bt + (size_t)(bn + row) * K + k0 + kc * 8;
            __builtin_amdgcn_global_load_lds(
                (const __attribute__((address_space(1))) void*)gb0,
                (__attribute__((address_space(3))) void*)(Bls0 + chunk * 8), 16, 0, 0);
            const ushort* gb1 = gb0 + 32;
            __builtin_amdgcn_global_load_lds(
                (const __attribute__((address_space(1))) void*)gb1,
                (__attribute__((address_space(3))) void*)(Bls1 + chunk * 8), 16, 0, 0);
        }
        __syncthreads();

        short8 af[4][2], bfr[JF][2];
        #pragma unroll
        for (int i = 0; i < 4; ++i) {
            af[i][0] = *(const short8*)&Als0[(wm + i * 16 + fm) * 32 + kg * 8];
            af[i][1] = *(const short8*)&Als1[(wm + i * 16 + fm) * 32 + kg * 8];
        }
        #pragma unroll
        for (int j = 0; j < JF; ++j) {
            bfr[j][0] = *(const short8*)&Bls0[(wn + j * 16 + fm) * 32 + kg * 8];
            bfr[j][1] = *(const short8*)&Bls1[(wn + j * 16 + fm) * 32 + kg * 8];
        }
        #pragma unroll
        for (int i = 0; i < 4; ++i)
            #pragma unroll
            for (int j = 0; j < JF; ++j) {
                acc[i][j] = __builtin_amdgcn_mfma_f32_16x16x32_bf16(
                    af[i][0], bfr[j][0], acc[i][j], 0, 0, 0);
                acc[i][j] = __builtin_amdgcn_mfma_f32_16x16x32_bf16(
                    af[i][1], bfr[j][1], acc[i][j], 0, 0, 0);
            }
        __syncthreads();
    }

    float* Pz = P + (size_t)blockIdx.z * M * N;
    const int orow0 = (lane >> 4) * 4;
    const int ocol = lane & 15;
    #pragma unroll
    for (int j = 0; j < JF; ++j) {
        const int n = bn + wn + j * 16 + ocol;
        #pragma unroll
        for (int i = 0; i < 4; ++i) {
            const int m0 = bm + wm + i * 16 + orow0;
            #pragma unroll
            for (int r = 0; r < 4; ++r)
                Pz[(size_t)(m0 + r) * N + n] = acc[i][j][r];
        }
    }
}

// ---------------- MFMA flash attention, lean softmax ----------------
__global__ __launch_bounds__(256, 3)
void attn_mfma(const ushort* __restrict__ QKVb, const ushort* __restrict__ Vt,
               const ushort* __restrict__ biasw, const int* __restrict__ mask,
               ushort* __restrict__ ctx) {
    const int q0 = blockIdx.x * 64;
    const int h = blockIdx.y;
    const int b = blockIdx.z;
    const int t = threadIdx.x;
    const int lane = t & 63;
    const int w = t >> 6;
    const int g = lane >> 4;
    const int c = lane & 15;

    __shared__ ushort QP[64 * 72];
    __shared__ ushort Ks[64 * 72];
    __shared__ ushort Vs[64 * 72];
    __shared__ int maskS[LL];

    #pragma unroll
    for (int i = 0; i < 2; ++i) {
        const int chunk = i * 256 + t;
        const int row = chunk >> 3, c8 = (chunk & 7) * 8;
        *(short8*)&QP[row * 72 + c8] =
            *(const short8*)(QKVb + ((size_t)(b * LL + q0 + row)) * LDQ + h * DHH + c8);
    }
    ((int4*)maskS)[t] = ((const int4*)(mask + b * LL))[t];

    short8 pk[2], pv[2];
    #pragma unroll
    for (int i = 0; i < 2; ++i) {
        const int chunk = i * 256 + t;
        const int row = chunk >> 3, c8 = (chunk & 7) * 8;
        pk[i] = *(const short8*)(QKVb + ((size_t)(b * LL + row)) * LDQ + 1024 + h * DHH + c8);
        pv[i] = *(const short8*)(Vt + ((size_t)((b * HH + h) * DHH + row)) * LL + c8);
    }
    __syncthreads();

    short8 aq0 = *(const short8*)&QP[(w * 16 + c) * 72 + g * 8];
    short8 aq1 = *(const short8*)&QP[(w * 16 + c) * 72 + g * 8 + 32];
    ushort* Pw = QP + w * (16 * 72);

    float m_pr[4] = {-3.4e38f, -3.4e38f, -3.4e38f, -3.4e38f};
    float l_run[4] = {0.f, 0.f, 0.f, 0.f};
    f32x4 acc_o[4] = {};

    for (int kt = 0; kt < 16; ++kt) {
        #pragma unroll
        for (int i = 0; i < 2; ++i) {
            const int chunk = i * 256 + t;
            const int row = chunk >> 3, c8 = (chunk & 7) * 8;
            *(short8*)&Ks[row * 72 + c8] = pk[i];
            *(short8*)&Vs[row * 72 + c8] = pv[i];
        }
        __syncthreads();

        if (kt < 15) {
            const int k0n = (kt + 1) * 64;
            #pragma unroll
            for (int i = 0; i < 2; ++i) {
                const int chunk = i * 256 + t;
                const int row = chunk >> 3, c8 = (chunk & 7) * 8;
                pk[i] = *(const short8*)(QKVb + ((size_t)(b * LL + k0n + row)) * LDQ + 1024 + h * DHH + c8);
                pv[i] = *(const short8*)(Vt + ((size_t)((b * HH + h) * DHH + row)) * LL + k0n + c8);
            }
        }

        ushort4 pb[4];
        #pragma unroll
        for (int r = 0; r < 4; ++r) {
            const int q = q0 + w * 16 + 4 * g + r;
            pb[r] = *(const ushort4*)&biasw[((size_t)(b * LL + q) * 16 + kt) * 64 + c * 4];
        }
        int mk[4];
        #pragma unroll
        for (int j = 0; j < 4; ++j) mk[j] = maskS[kt * 64 + j * 16 + c];

        f32x4 accs[4] = {};
        #pragma unroll
        for (int j = 0; j < 4; ++j) {
            short8 bk0 = *(const short8*)&Ks[(j * 16 + c) * 72 + g * 8];
            short8 bk1 = *(const short8*)&Ks[(j * 16 + c) * 72 + g * 8 + 32];
            accs[j] = __builtin_amdgcn_mfma_f32_16x16x32_bf16(aq0, bk0, accs[j], 0, 0, 0);
            accs[j] = __builtin_amdgcn_mfma_f32_16x16x32_bf16(aq1, bk1, accs[j], 0, 0, 0);
        }

        float sc[4][4];
        #pragma unroll
        for (int j = 0; j < 4; ++j)
            #pragma unroll
            for (int r = 0; r < 4; ++r) {
                const float bw = bf2f(((const ushort*)&pb[r])[j]);
                const float v = accs[j][r] * bw;
                sc[j][r] = (mk[j] == 0) ? -14427.0f : v;
            }

        float mt[4];
        #pragma unroll
        for (int r = 0; r < 4; ++r)
            mt[r] = fmaxf(fmaxf(sc[0][r], sc[1][r]), fmaxf(sc[2][r], sc[3][r]));
        #pragma unroll
        for (int d = 1; d < 16; d <<= 1)
            #pragma unroll
            for (int r = 0; r < 4; ++r)
                mt[r] = fmaxf(mt[r], __shfl_xor(mt[r], d));

        float al[4], lt[4];
        #pragma unroll
        for (int r = 0; r < 4; ++r) {
            const float mn = fmaxf(m_pr[r], mt[r]);
            al[r] = fexp2(m_pr[r] - mn);
            m_pr[r] = mn;
            lt[r] = 0.0f;
        }

        #pragma unroll
        for (int j = 0; j < 4; ++j)
            #pragma unroll
            for (int r = 0; r < 4; ++r) {
                const float pe = fexp2(sc[j][r] - m_pr[r]);
                lt[r] += pe;
                Pw[(4 * g + r) * 72 + j * 16 + c] = f2bf(pe);
            }

        const bool ones = (al[0] == 1.0f) & (al[1] == 1.0f) &
                          (al[2] == 1.0f) & (al[3] == 1.0f);
        if (!__all(ones)) {
            #pragma unroll
            for (int r = 0; r < 4; ++r) l_run[r] *= al[r];
            #pragma unroll
            for (int j = 0; j < 4; ++j)
                #pragma unroll
                for (int r = 0; r < 4; ++r)
                    acc_o[j][r] *= al[r];
        }
        #pragma unroll
        for (int r = 0; r < 4; ++r) l_run[r] += lt[r];

        #pragma unroll
        for (int ks = 0; ks < 2; ++ks) {
            short8 ap = *(const short8*)&Pw[c * 72 + ks * 32 + g * 8];
            #pragma unroll
            for (int j = 0; j < 4; ++j) {
                short8 bv8 = *(const short8*)&Vs[(j * 16 + c) * 72 + ks * 32 + g * 8];
                acc_o[j] = __builtin_amdgcn_mfma_f32_16x16x32_bf16(ap, bv8, acc_o[j], 0, 0, 0);
            }
        }
        __syncthreads();
    }

    #pragma unroll
    for (int r = 0; r < 4; ++r) {
        float l = l_run[r];
        #pragma unroll
        for (int d = 1; d < 16; d <<= 1) l += __shfl_xor(l, d);
        const float inv = 1.0f / l;
        #pragma unroll
        for (int j = 0; j < 4; ++j)
            ctx[((size_t)(b * LL + q0 + w * 16 + 4 * g + r)) * DD + h * DHH + j * 16 + c] =
                f2bf(acc_o[j][r] * inv);
    }
}

// ---------------- split-K reduce + col-bias + residual + LayerNorm ---------
// v = P0 + P1 + cb[col] + bres;  out = gamma*(v-mean)*rstd + beta  (+bf16 copy)
__global__ __launch_bounds__(256)
void add_ln_kernel(const float* __restrict__ P0, const float* __restrict__ P1,
                   const float* __restrict__ cb, const float* __restrict__ bres,
                   const float* __restrict__ gamma, const float* __restrict__ beta,
                   float* __restrict__ out, ushort* __restrict__ outb) {
    const int row = blockIdx.x;
    const int tid = threadIdx.x;
    __shared__ float red[256];

    const size_t base = (size_t)row * DD;
    float v[4];
    float sum = 0.0f;
    #pragma unroll
    for (int i = 0; i < 4; ++i) {
        const int col = tid + i * 256;
        v[i] = P0[base + col] + P1[base + col] + cb[col] + bres[base + col];
        sum += v[i];
    }
    const float mean = block_reduce_sum(sum, red, tid) * (1.0f / 1024.0f);
    float vs = 0.0f;
    #pragma unroll
    for (int i = 0; i < 4; ++i) {
        const float dlt = v[i] - mean;
        vs += dlt * dlt;
    }
    const float var = block_reduce_sum(vs, red, tid) * (1.0f / 1024.0f);
    const float rstd = rsqrtf(var + 1e-12f);
    #pragma unroll
    for (int i = 0; i < 4; ++i) {
        const int col = tid + i * 256;
        const float o = gamma[col] * (v[i] - mean) * rstd + beta[col];
        out[base + col] = o;
        if (outb) outb[base + col] = f2bf(o);
    }
}

extern "C" void kernel_launch(void* const* d_in, const int* in_sizes, int n_in,
                              void* d_out, int out_size, void* d_ws, size_t ws_size,
                              hipStream_t stream) {
    const float* x         = (const float*)d_in[0];
    const float* attn_bias = (const float*)d_in[1];
    const int*   src_mask  = (const int*)  d_in[2];
    const float* wq = (const float*)d_in[3];
    const float* bq = (const float*)d_in[4];
    const float* wk = (const float*)d_in[5];
    const float* bk = (const float*)d_in[6];
    const float* wv = (const float*)d_in[7];
    const float* bv = (const float*)d_in[8];
    const float* wo = (const float*)d_in[9];
    const float* bo = (const float*)d_in[10];
    const float* gamma1 = (const float*)d_in[11];
    const float* beta1  = (const float*)d_in[12];
    const float* w1 = (const float*)d_in[13];
    const float* b1 = (const float*)d_in[14];
    const float* w2 = (const float*)d_in[15];
    const float* b2 = (const float*)d_in[16];
    const float* gamma2 = (const float*)d_in[17];
    const float* beta2  = (const float*)d_in[18];
    float* out = (float*)d_out;

    // workspace arena (96 MB, time-multiplexed)
    // 0-8:    xb -> ctxb -> W1T
    // 8-32:   QKVb (dead after attn) -> Hb(8-24) + Hbb(24-32); Hbb -> W2T after FFN1
    // 32-64:  F1b (FFN1 out)
    // 40-48:  Vt (during QKV+attn; dead before F1b written)
    // 48-54:  WQKVT -> WOT(48-50)
    // 62:     bqkv
    // 64-96:  biasw(64-72.4, dead after attn) -> P0(64-80) + P1(80-96)
    const size_t MB = 1024 * 1024;
    char* W = (char*)d_ws;
    ushort* xb    = (ushort*)(W + 0);
    ushort* ctxb  = (ushort*)(W + 0);
    ushort* W1T   = (ushort*)(W + 0);
    ushort* QKVb  = (ushort*)(W + 8 * MB);
    float*  Hb    = (float*) (W + 8 * MB);
    ushort* Hbb   = (ushort*)(W + 24 * MB);
    ushort* W2T   = (ushort*)(W + 24 * MB);
    ushort* F1b   = (ushort*)(W + 32 * MB);
    ushort* Vt    = (ushort*)(W + 40 * MB);
    ushort* WQKVT = (ushort*)(W + 48 * MB);
    ushort* WOT   = (ushort*)(W + 48 * MB);
    float*  bqkv  = (float*) (W + 62 * MB);
    ushort* biasw = (ushort*)(W + 64 * MB);
    float*  P0    = (float*) (W + 64 * MB);   // P1 = P0 + MM*DD

    dim3 blk(256);

    // 1. cast x -> bf16; pre-swizzle attn_bias
    cast_bf16<<<dim3(4096), blk, 0, stream>>>(x, xb);
    swizzle_bias<<<dim3(4096), blk, 0, stream>>>(attn_bias, biasw);
    // 2. QKV weight transposes + bias concat
    transpose_cast<<<dim3(32, 32), blk, 0, stream>>>(wq, WQKVT, DD, DD);
    transpose_cast<<<dim3(32, 32), blk, 0, stream>>>(wk, WQKVT + 1024 * 1024, DD, DD);
    transpose_cast<<<dim3(32, 32), blk, 0, stream>>>(wv, WQKVT + 2048 * 1024, DD, DD);
    concat3<<<dim3(12), blk, 0, stream>>>(bq, bk, bv, bqkv);
    // 3. fused QKV projection (bf16 out; Q scaled 0.125; V -> Vt transposed)
    gemm_bf16<128><<<dim3(24, 32), blk, 0, stream>>>(xb, WQKVT, bqkv, QKVb,
                                                     Vt, 2048, MM, LDQ, DD, 0, 1, 1024);
    // 4. MFMA flash attention -> ctx bf16
    attn_mfma<<<dim3(16, HH, BB), blk, 0, stream>>>(QKVb, Vt, biasw, src_mask, ctxb);
    // 5. WO transpose + split-K output projection -> P0/P1
    transpose_cast<<<dim3(32, 32), blk, 0, stream>>>(wo, WOT, DD, DD);
    gemm_bf16_sk<64><<<dim3(16, 32, 2), blk, 0, stream>>>(ctxb, WOT, P0, MM, DD, DD);
    // 6. W1 transpose into dead ctxb region (ctxb consumed by WO gemm above)
    transpose_cast<<<dim3(128, 32), blk, 0, stream>>>(w1, W1T, DD, FFF);
    // 7. h = LN(P0+P1+bo + x), fp32 + bf16
    add_ln_kernel<<<dim3(MM), blk, 0, stream>>>(P0, P0 + (size_t)MM * DD, bo, x,
                                                gamma1, beta1, Hb, Hbb);
    // 8. FFN1 (relu, bf16 out)
    gemm_bf16<128><<<dim3(32, 32), blk, 0, stream>>>(Hbb, W1T, b1, F1b,
                                                     Vt, 1 << 30, MM, FFF, DD, 1, 1, 0);
    // 9. W2 transpose into dead Hbb region; split-K FFN2 -> P0/P1
    transpose_cast<<<dim3(32, 128), blk, 0, stream>>>(w2, W2T, FFF, DD);
    gemm_bf16_sk<64><<<dim3(16, 32, 2), blk, 0, stream>>>(F1b, W2T, P0, MM, DD, FFF);
    // 10. out = LN(P0+P1+b2 + h)
    add_ln_kernel<<<dim3(MM), blk, 0, stream>>>(P0, P0 + (size_t)MM * DD, b2, Hb,
                                                gamma2, beta2, out, nullptr);
}